// Round 5
// baseline (2063.803 us; speedup 1.0000x reference)
//
#include <hip/hip_runtime.h>
#include <math.h>

// Problem constants (ResidualVQ: B=8, N=4096, D=512, C=1024, Q=8)
#define B_   8
#define N_   4096
#define D_   512
#define C_   1024
#define Q_   8
#define ROWS (B_ * N_)   // 32768 token rows

#define TAU  0.1f        // rescue margin; approx-score error bound ~5e-4
#define RCH  8           // rows per rescue chunk

typedef __attribute__((ext_vector_type(8))) short bf16x8;
typedef __attribute__((ext_vector_type(4))) float f32x4;

// round-to-nearest-even f32 -> bf16 (bits)
__device__ __forceinline__ unsigned short bf16rn(float f) {
    unsigned int u = __builtin_bit_cast(unsigned int, f);
    return (unsigned short)((u + 0x7fffu + ((u >> 16) & 1u)) >> 16);
}
__device__ __forceinline__ float bf16f(unsigned short h) {
    unsigned int u = ((unsigned int)h) << 16;
    return __builtin_bit_cast(float, u);
}
// LDS byte offset for tile [row][32 bf16], XOR-swizzled (<=2-way conflicts)
__device__ __forceinline__ int swzoff(int row, int q) {
    return row * 64 + ((q ^ ((row >> 1) & 3)) << 4);
}

// -------------------------------------------------------------------------
// f32 -> hi/lo bf16 (used for codebooks once per call, and for x at stage 0)
__global__ __launch_bounds__(256)
void cb_convert_kernel(const float* __restrict__ cb,
                       unsigned short* __restrict__ hi,
                       unsigned short* __restrict__ lo) {
    const int i4 = blockIdx.x * 256 + threadIdx.x;      // float4 index
    float4 v = ((const float4*)cb)[i4];
    ushort4 h, l;
    h.x = bf16rn(v.x); l.x = bf16rn(v.x - bf16f(h.x));
    h.y = bf16rn(v.y); l.y = bf16rn(v.y - bf16f(h.y));
    h.z = bf16rn(v.z); l.z = bf16rn(v.z - bf16f(h.z));
    h.w = bf16rn(v.w); l.w = bf16rn(v.w - bf16f(h.w));
    ((ushort4*)hi)[i4] = h;
    ((ushort4*)lo)[i4] = l;
}

// ||e||^2 for every code of every stage (exact f32)
__global__ __launch_bounds__(256)
void code_norms_kernel(const float* __restrict__ cb, float* __restrict__ norms) {
    const int code = blockIdx.x * 4 + (threadIdx.x >> 6);
    const int lane = threadIdx.x & 63;
    const float* p = cb + (size_t)code * D_;
    float s = 0.f;
    #pragma unroll
    for (int d = lane * 4; d < D_; d += 256) {
        float4 v = *(const float4*)(p + d);
        s += v.x * v.x + v.y * v.y + v.z * v.z + v.w * v.w;
    }
    #pragma unroll
    for (int m = 1; m < 64; m <<= 1) s += __shfl_xor(s, m);
    if (lane == 0) norms[code] = s;
}

// -------------------------------------------------------------------------
// Split-bf16 MFMA scoring GEMM with per-row top-2 tracking.
// grid = (ROWS/128, 2 halves of C). Block: 256 thr = 4 waves (2 row x 2 code).
// PRECONV=1: A hi/lo preconverted in global (pure-copy staging).
// PRECONV=0: fallback, convert A f32->hi/lo in the loop (round-4 behavior).
template<int PRECONV>
__global__ __launch_bounds__(256, 2)
void rvq_gemm_kernel(const float* __restrict__ src,          // residual f32 [ROWS][D_]
                     const unsigned short* __restrict__ ahi, // residual hi  (PRECONV)
                     const unsigned short* __restrict__ alo, // residual lo  (PRECONV)
                     const unsigned short* __restrict__ cbh, // stage cb hi [C_][D_]
                     const unsigned short* __restrict__ cbl, // stage cb lo
                     const float* __restrict__ norms_s,      // [C_]
                     float* __restrict__ st_m1,              // [4][ROWS]
                     float* __restrict__ st_m2,              // [4][ROWS]
                     int* __restrict__ st_i1)                // [4][ROWS]
{
    __shared__ char lds[32768];
    char* AhiB = lds;
    char* AloB = lds + 8192;
    char* BhiB = lds + 16384;
    char* BloB = lds + 24576;

    const int tid  = threadIdx.x;
    const int lane = tid & 63;
    const int lc   = lane & 15;        // code lane / row lane within frag
    const int lq   = lane >> 4;        // k-chunk of fragment
    const int wv   = tid >> 6;
    const int wr   = wv >> 1;          // wave row-half (0..1)
    const int wc   = wv & 1;           // wave code-half (0..1)
    const int rowBase = blockIdx.x * 128;
    const int half = blockIdx.y;

    float c_m1 = INFINITY, c_m2 = INFINITY;
    int   c_i1 = 0;

    const int arow  = tid >> 1;        // 0..127
    const int ahalf = tid & 1;         // which 16-k half

    for (int chunk = 0; chunk < 4; ++chunk) {
        const int codeBase = half * 512 + chunk * 128;
        f32x4 acc[4][4];
        #pragma unroll
        for (int m = 0; m < 4; ++m)
            #pragma unroll
            for (int n = 0; n < 4; ++n) acc[m][n] = (f32x4){0.f, 0.f, 0.f, 0.f};

        for (int kt = 0; kt < D_ / 32; ++kt) {
            __syncthreads();   // previous compute finished before restaging
            // ---- stage A
            if constexpr (PRECONV) {
                const size_t aoff = (size_t)(rowBase + arow) * D_ + kt * 32 + ahalf * 16;
                bf16x8 H0 = *(const bf16x8*)(ahi + aoff);
                bf16x8 H1 = *(const bf16x8*)(ahi + aoff + 8);
                bf16x8 L0 = *(const bf16x8*)(alo + aoff);
                bf16x8 L1 = *(const bf16x8*)(alo + aoff + 8);
                const int q0 = ahalf * 2;
                *(bf16x8*)(AhiB + swzoff(arow, q0))     = H0;
                *(bf16x8*)(AhiB + swzoff(arow, q0 + 1)) = H1;
                *(bf16x8*)(AloB + swzoff(arow, q0))     = L0;
                *(bf16x8*)(AloB + swzoff(arow, q0 + 1)) = L1;
            } else {
                const float* ap = src + (size_t)(rowBase + arow) * D_ + kt * 32 + ahalf * 16;
                float fv[16];
                *(float4*)&fv[0]  = ((const float4*)ap)[0];
                *(float4*)&fv[4]  = ((const float4*)ap)[1];
                *(float4*)&fv[8]  = ((const float4*)ap)[2];
                *(float4*)&fv[12] = ((const float4*)ap)[3];
                bf16x8 H0, H1, L0, L1;
                #pragma unroll
                for (int j = 0; j < 8; ++j) {
                    unsigned short h0 = bf16rn(fv[j]);
                    H0[j] = (short)h0;
                    L0[j] = (short)bf16rn(fv[j] - bf16f(h0));
                    unsigned short h1 = bf16rn(fv[j + 8]);
                    H1[j] = (short)h1;
                    L1[j] = (short)bf16rn(fv[j + 8] - bf16f(h1));
                }
                const int q0 = ahalf * 2;
                *(bf16x8*)(AhiB + swzoff(arow, q0))     = H0;
                *(bf16x8*)(AhiB + swzoff(arow, q0 + 1)) = H1;
                *(bf16x8*)(AloB + swzoff(arow, q0))     = L0;
                *(bf16x8*)(AloB + swzoff(arow, q0 + 1)) = L1;
            }
            // ---- stage B (pre-converted bf16 hi/lo)
            {
                const size_t boff = (size_t)(codeBase + arow) * D_ + kt * 32 + ahalf * 16;
                bf16x8 bh0 = *(const bf16x8*)(cbh + boff);
                bf16x8 bh1 = *(const bf16x8*)(cbh + boff + 8);
                bf16x8 bl0 = *(const bf16x8*)(cbl + boff);
                bf16x8 bl1 = *(const bf16x8*)(cbl + boff + 8);
                const int q0 = ahalf * 2;
                *(bf16x8*)(BhiB + swzoff(arow, q0))     = bh0;
                *(bf16x8*)(BhiB + swzoff(arow, q0 + 1)) = bh1;
                *(bf16x8*)(BloB + swzoff(arow, q0))     = bl0;
                *(bf16x8*)(BloB + swzoff(arow, q0 + 1)) = bl1;
            }
            __syncthreads();
            // ---- fragments + MFMA (3 split terms, shared accumulator)
            bf16x8 ah[4], al[4], bh[4], bl[4];
            #pragma unroll
            for (int m = 0; m < 4; ++m) {
                const int r = wr * 64 + m * 16 + lc;
                ah[m] = *(const bf16x8*)(AhiB + swzoff(r, lq));
                al[m] = *(const bf16x8*)(AloB + swzoff(r, lq));
            }
            #pragma unroll
            for (int n = 0; n < 4; ++n) {
                const int c = wc * 64 + n * 16 + lc;
                bh[n] = *(const bf16x8*)(BhiB + swzoff(c, lq));
                bl[n] = *(const bf16x8*)(BloB + swzoff(c, lq));
            }
            #pragma unroll
            for (int m = 0; m < 4; ++m)
                #pragma unroll
                for (int n = 0; n < 4; ++n) {
                    acc[m][n] = __builtin_amdgcn_mfma_f32_16x16x32_bf16(ah[m], bh[n], acc[m][n], 0, 0, 0);
                    acc[m][n] = __builtin_amdgcn_mfma_f32_16x16x32_bf16(ah[m], bl[n], acc[m][n], 0, 0, 0);
                    acc[m][n] = __builtin_amdgcn_mfma_f32_16x16x32_bf16(al[m], bh[n], acc[m][n], 0, 0, 0);
                }
        }

        // ---- fold chunk scores into carried top-2
        const int cbase = codeBase + wc * 64;
        const float nrm0 = norms_s[cbase + lc];
        const float nrm1 = norms_s[cbase + 16 + lc];
        const float nrm2 = norms_s[cbase + 32 + lc];
        const float nrm3 = norms_s[cbase + 48 + lc];
        #pragma unroll
        for (int m = 0; m < 4; ++m) {
            #pragma unroll
            for (int r = 0; r < 4; ++r) {
                float s0 = fmaf(-2.f, acc[m][0][r], nrm0);
                float s1 = fmaf(-2.f, acc[m][1][r], nrm1);
                float s2 = fmaf(-2.f, acc[m][2][r], nrm2);
                float s3 = fmaf(-2.f, acc[m][3][r], nrm3);
                float m1 = s0, m2 = INFINITY;
                int   i1 = cbase + lc;
                if (s1 < m1) { m2 = m1; m1 = s1; i1 = cbase + 16 + lc; } else m2 = fminf(m2, s1);
                if (s2 < m1) { m2 = m1; m1 = s2; i1 = cbase + 32 + lc; } else m2 = fminf(m2, s2);
                if (s3 < m1) { m2 = m1; m1 = s3; i1 = cbase + 48 + lc; } else m2 = fminf(m2, s3);
                #pragma unroll
                for (int d = 1; d < 16; d <<= 1) {
                    float om1 = __shfl_xor(m1, d);
                    int   oi1 = __shfl_xor(i1, d);
                    float om2 = __shfl_xor(m2, d);
                    bool take = (om1 < m1) || (om1 == m1 && oi1 < i1);
                    float lose1 = take ? m1 : om1;
                    m2 = fminf(fminf(m2, om2), lose1);
                    m1 = take ? om1 : m1;
                    i1 = take ? oi1 : i1;
                }
                if (lc == (m * 4 + r)) {
                    bool take = (m1 < c_m1) || (m1 == c_m1 && i1 < c_i1);
                    float lose1 = take ? c_m1 : m1;
                    c_m2 = fminf(fminf(c_m2, m2), lose1);
                    c_m1 = take ? m1 : c_m1;
                    c_i1 = take ? i1 : c_i1;
                }
            }
        }
    }

    const int myrow = rowBase + wr * 64 + (lc >> 2) * 16 + lq * 4 + (lc & 3);
    const int quarter = half * 2 + wc;
    st_m1[quarter * ROWS + myrow] = c_m1;
    st_m2[quarter * ROWS + myrow] = c_m2;
    st_i1[quarter * ROWS + myrow] = c_i1;
}

// -------------------------------------------------------------------------
// merge 4 quarters -> final idx; near-tie rows appended to compact rescue list
__global__ __launch_bounds__(256)
void merge_kernel(const float* __restrict__ st_m1, const float* __restrict__ st_m2,
                  const int* __restrict__ st_i1,
                  int* __restrict__ idx_i, float* __restrict__ idx_f,
                  int* __restrict__ list, int* __restrict__ nflag, int q) {
    const int row = blockIdx.x * 256 + threadIdx.x;
    float m1 = st_m1[row], m2 = st_m2[row];
    int   i1 = st_i1[row];
    #pragma unroll
    for (int qt = 1; qt < 4; ++qt) {
        float om1 = st_m1[qt * ROWS + row];
        float om2 = st_m2[qt * ROWS + row];
        int   oi1 = st_i1[qt * ROWS + row];
        if (om1 < m1) { m2 = fminf(m1, om2); m1 = om1; i1 = oi1; }
        else          { m2 = fminf(m2, om1); }
    }
    idx_i[row] = i1;
    idx_f[(size_t)row * Q_ + q] = (float)i1;
    if (m2 - m1 < TAU) {
        const int p = atomicAdd(nflag, 1);
        list[p] = row;
    }
}

// -------------------------------------------------------------------------
// Exact-f32 re-argmin for near-tie rows, compact-list driven.
__global__ __launch_bounds__(256)
void rescue_kernel(const float* __restrict__ src, const float* __restrict__ cb,
                   const float* __restrict__ norms_s,
                   const int* __restrict__ list, const int* __restrict__ nflag_p,
                   int* __restrict__ idx_i, float* __restrict__ idx_f, int q)
{
    __shared__ float As[D_][RCH];      // residual rows, [k][row] (16 KB)
    __shared__ int   rows_s[RCH];
    __shared__ float wm[4][RCH];
    __shared__ int   wi[4][RCH];
    const int nflag = nflag_p[0];
    const int tid = threadIdx.x;

    for (int chunk = blockIdx.x; chunk * RCH < nflag; chunk += gridDim.x) {
        __syncthreads();   // previous chunk's readers done before overwrite
        if (tid < RCH) {
            const int li = chunk * RCH + tid;
            rows_s[tid] = list[li < nflag ? li : nflag - 1];   // pad = dup last
        }
        __syncthreads();
        #pragma unroll
        for (int i = 0; i < 4; ++i) {
            const int v  = tid + 256 * i;       // float4 unit 0..1023
            const int r  = v >> 7;
            const int k4 = (v & 127) * 4;
            float4 f = *(const float4*)(src + (size_t)rows_s[r] * D_ + k4);
            As[k4 + 0][r] = f.x; As[k4 + 1][r] = f.y;
            As[k4 + 2][r] = f.z; As[k4 + 3][r] = f.w;
        }
        __syncthreads();

        float acc[4][RCH];
        #pragma unroll
        for (int j = 0; j < 4; ++j)
            #pragma unroll
            for (int r = 0; r < RCH; ++r) acc[j][r] = 0.f;

        for (int k = 0; k < D_; k += 4) {
            float4 bq[4];
            #pragma unroll
            for (int j = 0; j < 4; ++j)
                bq[j] = *(const float4*)(cb + (size_t)(tid + 256 * j) * D_ + k);
            const float* bp = (const float*)&bq[0];
            const float* ap = &As[k][0];        // 32 consecutive floats, uniform addr
            #pragma unroll
            for (int e = 0; e < 4; ++e)
                #pragma unroll
                for (int r = 0; r < RCH; ++r) {
                    const float a = ap[e * RCH + r];
                    #pragma unroll
                    for (int j = 0; j < 4; ++j)
                        acc[j][r] = fmaf(bp[j * 4 + e], a, acc[j][r]);
                }
        }

        float m1[RCH]; int i1[RCH];
        #pragma unroll
        for (int r = 0; r < RCH; ++r) { m1[r] = INFINITY; i1[r] = 0; }
        #pragma unroll
        for (int j = 0; j < 4; ++j) {
            const int c = tid + 256 * j;
            const float nr = norms_s[c];
            #pragma unroll
            for (int r = 0; r < RCH; ++r) {
                const float s = fmaf(-2.f, acc[j][r], nr);
                if (s < m1[r]) { m1[r] = s; i1[r] = c; }
            }
        }
        #pragma unroll
        for (int d = 1; d < 64; d <<= 1)
            #pragma unroll
            for (int r = 0; r < RCH; ++r) {
                const float om = __shfl_xor(m1[r], d);
                const int   oi = __shfl_xor(i1[r], d);
                if (om < m1[r] || (om == m1[r] && oi < i1[r])) { m1[r] = om; i1[r] = oi; }
            }
        if ((tid & 63) == 0)
            #pragma unroll
            for (int r = 0; r < RCH; ++r) { wm[tid >> 6][r] = m1[r]; wi[tid >> 6][r] = i1[r]; }
        __syncthreads();
        if (tid < RCH) {
            float bm = wm[0][tid]; int bi = wi[0][tid];
            #pragma unroll
            for (int w = 1; w < 4; ++w)
                if (wm[w][tid] < bm || (wm[w][tid] == bm && wi[w][tid] < bi)) {
                    bm = wm[w][tid]; bi = wi[w][tid];
                }
            const int li = chunk * RCH + tid;
            if (li < nflag) {
                const int row = rows_s[tid];
                idx_i[row] = bi;
                idx_f[(size_t)row * Q_ + q] = (float)bi;
            }
        }
    }
}

// -------------------------------------------------------------------------
// residual update: newres = res - cb[idx] (exact f32); loss; final qout.
// write_hl: also emit bf16 hi/lo of newres for the next stage's GEMM A.
__global__ __launch_bounds__(256)
void update_kernel(const float* __restrict__ src, float* __restrict__ dst,
                   const float* __restrict__ x, const float* __restrict__ cb,
                   const int* __restrict__ idx_i, float* __restrict__ loss_out,
                   unsigned short* __restrict__ rhi, unsigned short* __restrict__ rlo,
                   int is_last, int write_hl) {
    __shared__ int ids[64];
    const int tid = threadIdx.x;
    const int rowBase = blockIdx.x * 64;
    if (tid < 64) ids[tid] = idx_i[rowBase + tid];
    __syncthreads();
    float lsum = 0.f;
    #pragma unroll 4
    for (int e4 = tid; e4 < 64 * D_ / 4; e4 += 256) {
        const int row  = e4 >> 7;
        const int d    = (e4 & 127) * 4;
        const int code = ids[row];
        const size_t off = (size_t)(rowBase + row) * D_ + d;
        float4 r = *(const float4*)(src + off);
        float4 e = *(const float4*)(cb + (size_t)code * D_ + d);
        float4 nr = make_float4(r.x - e.x, r.y - e.y, r.z - e.z, r.w - e.w);
        lsum += nr.x * nr.x + nr.y * nr.y + nr.z * nr.z + nr.w * nr.w;
        if (is_last) {
            float4 xv = *(const float4*)(x + off);
            *(float4*)(dst + off) = make_float4(xv.x - nr.x, xv.y - nr.y,
                                                xv.z - nr.z, xv.w - nr.w);
        } else {
            *(float4*)(dst + off) = nr;
        }
        if (write_hl) {
            ushort4 h, l;
            h.x = bf16rn(nr.x); l.x = bf16rn(nr.x - bf16f(h.x));
            h.y = bf16rn(nr.y); l.y = bf16rn(nr.y - bf16f(h.y));
            h.z = bf16rn(nr.z); l.z = bf16rn(nr.z - bf16f(h.z));
            h.w = bf16rn(nr.w); l.w = bf16rn(nr.w - bf16f(h.w));
            *(ushort4*)(rhi + off) = h;
            *(ushort4*)(rlo + off) = l;
        }
    }
    #pragma unroll
    for (int m = 1; m < 64; m <<= 1) lsum += __shfl_xor(lsum, m);
    if ((tid & 63) == 0)
        atomicAdd(loss_out, lsum * (1.0f / ((float)ROWS * (float)D_)));
}

// -------------------------------------------------------------------------
extern "C" void kernel_launch(void* const* d_in, const int* in_sizes, int n_in,
                              void* d_out, int out_size, void* d_ws, size_t ws_size,
                              hipStream_t stream) {
    const float* x  = (const float*)d_in[0];   // [B,N,D]
    const float* cb = (const float*)d_in[1];   // [Q,C,D]

    float* qout   = (float*)d_out;                                  // doubles as residual
    float* idx_f  = (float*)d_out + (size_t)ROWS * D_;              // [ROWS][Q_] as floats
    float* losses = idx_f + (size_t)ROWS * Q_;                      // [Q_]

    char* w = (char*)d_ws;
    unsigned short* cb_hi = (unsigned short*)w;                     // Q*C*D bf16 (8MB)
    unsigned short* cb_lo = cb_hi + (size_t)Q_ * C_ * D_;           // 8MB
    float* norms = (float*)(cb_lo + (size_t)Q_ * C_ * D_);          // Q*C
    float* st_m1 = norms + Q_ * C_;                                 // 4*ROWS
    float* st_m2 = st_m1 + 4 * ROWS;
    int*   st_i1 = (int*)(st_m2 + 4 * ROWS);
    int*   idx_i = st_i1 + 4 * ROWS;                                // ROWS
    int*   list  = idx_i + ROWS;                                    // ROWS
    int*   nflag = list + ROWS;                                     // 64 (aligned pad)
    unsigned short* res_hi = (unsigned short*)(nflag + 64);         // ROWS*D (32MB)
    unsigned short* res_lo = res_hi + (size_t)ROWS * D_;            // 32MB

    const size_t need = (size_t)((char*)(res_lo + (size_t)ROWS * D_) - w);
    const int preconv = (ws_size >= need) ? 1 : 0;

    hipMemsetAsync(losses, 0, Q_ * sizeof(float), stream);
    cb_convert_kernel<<<Q_ * C_ * D_ / 1024, 256, 0, stream>>>(cb, cb_hi, cb_lo);
    code_norms_kernel<<<Q_ * C_ / 4, 256, 0, stream>>>(cb, norms);
    if (preconv)   // stage-0 A = x
        cb_convert_kernel<<<(int)((size_t)ROWS * D_ / 1024), 256, 0, stream>>>(x, res_hi, res_lo);

    for (int q = 0; q < Q_; ++q) {
        const float* src = (q == 0) ? x : qout;
        const float* cb_s = cb + (size_t)q * C_ * D_;
        if (preconv)
            rvq_gemm_kernel<1><<<dim3(ROWS / 128, 2), 256, 0, stream>>>(
                src, res_hi, res_lo,
                cb_hi + (size_t)q * C_ * D_, cb_lo + (size_t)q * C_ * D_,
                norms + (size_t)q * C_, st_m1, st_m2, st_i1);
        else
            rvq_gemm_kernel<0><<<dim3(ROWS / 128, 2), 256, 0, stream>>>(
                src, res_hi, res_lo,
                cb_hi + (size_t)q * C_ * D_, cb_lo + (size_t)q * C_ * D_,
                norms + (size_t)q * C_, st_m1, st_m2, st_i1);
        hipMemsetAsync(nflag, 0, sizeof(int), stream);
        merge_kernel<<<ROWS / 256, 256, 0, stream>>>(
            st_m1, st_m2, st_i1, idx_i, idx_f, list, nflag, q);
        rescue_kernel<<<256, 256, 0, stream>>>(
            src, cb_s, norms + (size_t)q * C_, list, nflag, idx_i, idx_f, q);
        update_kernel<<<ROWS / 64, 256, 0, stream>>>(
            src, qout, x, cb_s, idx_i, losses + q, res_hi, res_lo,
            (q == Q_ - 1) ? 1 : 0, (preconv && q < Q_ - 1) ? 1 : 0);
    }
}

// Round 6
// 2027.143 us; speedup vs baseline: 1.0181x; 1.0181x over previous
//
#include <hip/hip_runtime.h>
#include <math.h>

// Problem constants (ResidualVQ: B=8, N=4096, D=512, C=1024, Q=8)
#define B_   8
#define N_   4096
#define D_   512
#define C_   1024
#define Q_   8
#define ROWS (B_ * N_)   // 32768 token rows

#define TAU  0.1f        // rescue margin; approx-score error bound ~5e-4
#define RCH  8           // rows per rescue chunk

typedef __attribute__((ext_vector_type(8))) short bf16x8;
typedef __attribute__((ext_vector_type(4))) float f32x4;

// round-to-nearest-even f32 -> bf16 (bits)
__device__ __forceinline__ unsigned short bf16rn(float f) {
    unsigned int u = __builtin_bit_cast(unsigned int, f);
    return (unsigned short)((u + 0x7fffu + ((u >> 16) & 1u)) >> 16);
}
__device__ __forceinline__ float bf16f(unsigned short h) {
    unsigned int u = ((unsigned int)h) << 16;
    return __builtin_bit_cast(float, u);
}
// LDS byte offset for tile [row][32 bf16], XOR-swizzled (<=2-way conflicts)
__device__ __forceinline__ int swzoff(int row, int q) {
    return row * 64 + ((q ^ ((row >> 1) & 3)) << 4);
}
// async global->LDS, 16B per lane. LDS dest must be wave-uniform; global src per-lane.
__device__ __forceinline__ void gload16(const void* g, void* l) {
    __builtin_amdgcn_global_load_lds(
        (const __attribute__((address_space(1))) void*)g,
        (__attribute__((address_space(3))) void*)l, 16, 0, 0);
}

// -------------------------------------------------------------------------
// f32 -> hi/lo bf16 (codebooks once per call; x at stage 0)
__global__ __launch_bounds__(256)
void cb_convert_kernel(const float* __restrict__ cb,
                       unsigned short* __restrict__ hi,
                       unsigned short* __restrict__ lo) {
    const int i4 = blockIdx.x * 256 + threadIdx.x;      // float4 index
    float4 v = ((const float4*)cb)[i4];
    ushort4 h, l;
    h.x = bf16rn(v.x); l.x = bf16rn(v.x - bf16f(h.x));
    h.y = bf16rn(v.y); l.y = bf16rn(v.y - bf16f(h.y));
    h.z = bf16rn(v.z); l.z = bf16rn(v.z - bf16f(h.z));
    h.w = bf16rn(v.w); l.w = bf16rn(v.w - bf16f(h.w));
    ((ushort4*)hi)[i4] = h;
    ((ushort4*)lo)[i4] = l;
}

// ||e||^2 for every code of every stage (exact f32)
__global__ __launch_bounds__(256)
void code_norms_kernel(const float* __restrict__ cb, float* __restrict__ norms) {
    const int code = blockIdx.x * 4 + (threadIdx.x >> 6);
    const int lane = threadIdx.x & 63;
    const float* p = cb + (size_t)code * D_;
    float s = 0.f;
    #pragma unroll
    for (int d = lane * 4; d < D_; d += 256) {
        float4 v = *(const float4*)(p + d);
        s += v.x * v.x + v.y * v.y + v.z * v.z + v.w * v.w;
    }
    #pragma unroll
    for (int m = 1; m < 64; m <<= 1) s += __shfl_xor(s, m);
    if (lane == 0) norms[code] = s;
}

// -------------------------------------------------------------------------
// Pipelined split-bf16 MFMA scoring GEMM (T3-minimum schedule):
// double-buffered LDS; per step: STAGE(next) via global_load_lds -> ds_read ->
// 48 MFMA -> one barrier (vmcnt drain sits AFTER compute). Swizzled LDS kept
// via pre-swizzled global source (both-sides rule).
// grid = (ROWS/128, 2 C-halves). 4 waves: wave wv stages buffer wv.
__global__ __launch_bounds__(256, 2)
void rvq_gemm_pipe_kernel(const unsigned short* __restrict__ ahi, // residual hi [ROWS][D_]
                          const unsigned short* __restrict__ alo, // residual lo
                          const unsigned short* __restrict__ cbh, // stage cb hi [C_][D_]
                          const unsigned short* __restrict__ cbl, // stage cb lo
                          const float* __restrict__ norms_s,      // [C_]
                          float* __restrict__ st_m1,              // [4][ROWS]
                          float* __restrict__ st_m2,              // [4][ROWS]
                          int* __restrict__ st_i1)                // [4][ROWS]
{
    __shared__ char lds[65536];        // [db:2][buf:4(Ahi,Alo,Bhi,Blo)][8192]

    const int tid  = threadIdx.x;
    const int lane = tid & 63;
    const int lc   = lane & 15;        // code/row lane within frag
    const int lq   = lane >> 4;        // k-chunk of fragment
    const int wv   = tid >> 6;
    const int wr   = wv >> 1;          // wave row-half (0..1)
    const int wc   = wv & 1;           // wave code-half (0..1)
    const int rowBase = blockIdx.x * 128;
    const int half = blockIdx.y;

    // ---- staging role (wave wv owns buffer wv)
    const unsigned short* ssrc =
        (wv == 0) ? ahi : (wv == 1) ? alo : (wv == 2) ? cbh : cbl;
    const bool isA = (wv < 2);
    const int srow = lane >> 2;                    // 0..15 (row within 1KB issue)
    const int qsw  = (lane & 3) ^ ((srow >> 1) & 3); // inverse-swizzled k-slot
    char* const sbuf = lds + wv * 8192;

    auto STAGE = [&](int db, int c, int kt) {
        const int grow0 = isA ? rowBase : (half * 512 + c * 128);
        const unsigned short* p0 =
            ssrc + (size_t)(grow0 + srow) * D_ + kt * 32 + qsw * 8;
        char* lb = sbuf + db * 32768;
        #pragma unroll
        for (int i = 0; i < 8; ++i)                 // 8 x (64 lanes x 16B) = 8KB
            gload16(p0 + (size_t)i * 16 * D_, lb + i * 1024);
    };

    float c_m1 = INFINITY, c_m2 = INFINITY;
    int   c_i1 = 0;

    STAGE(0, 0, 0);
    __syncthreads();   // compiler drains vmcnt before barrier -> tile 0 ready

    for (int chunk = 0; chunk < 4; ++chunk) {
        const int codeBase = half * 512 + chunk * 128;
        f32x4 acc[4][4];
        #pragma unroll
        for (int m = 0; m < 4; ++m)
            #pragma unroll
            for (int n = 0; n < 4; ++n) acc[m][n] = (f32x4){0.f, 0.f, 0.f, 0.f};

        for (int kt = 0; kt < 16; ++kt) {
            const int t  = chunk * 16 + kt;
            const int db = t & 1;
            // prefetch next step into the other buffer (issue BEFORE compute)
            if (t + 1 < 64)
                STAGE(db ^ 1, (t + 1) >> 4, (t + 1) & 15);

            char* base = lds + db * 32768;
            char* AhiB = base;
            char* AloB = base + 8192;
            char* BhiB = base + 16384;
            char* BloB = base + 24576;

            bf16x8 ah[4], al[4], bh[4], bl[4];
            #pragma unroll
            for (int m = 0; m < 4; ++m) {
                const int r = wr * 64 + m * 16 + lc;
                ah[m] = *(const bf16x8*)(AhiB + swzoff(r, lq));
                al[m] = *(const bf16x8*)(AloB + swzoff(r, lq));
            }
            #pragma unroll
            for (int n = 0; n < 4; ++n) {
                const int c = wc * 64 + n * 16 + lc;
                bh[n] = *(const bf16x8*)(BhiB + swzoff(c, lq));
                bl[n] = *(const bf16x8*)(BloB + swzoff(c, lq));
            }
            #pragma unroll
            for (int m = 0; m < 4; ++m)
                #pragma unroll
                for (int n = 0; n < 4; ++n) {
                    acc[m][n] = __builtin_amdgcn_mfma_f32_16x16x32_bf16(ah[m], bh[n], acc[m][n], 0, 0, 0);
                    acc[m][n] = __builtin_amdgcn_mfma_f32_16x16x32_bf16(ah[m], bl[n], acc[m][n], 0, 0, 0);
                    acc[m][n] = __builtin_amdgcn_mfma_f32_16x16x32_bf16(al[m], bh[n], acc[m][n], 0, 0, 0);
                }
            // ONE barrier per step: ds_reads of buf[db] done (lgkmcnt), prefetch
            // for buf[db^1] committed (vmcnt) -> safe to swap.
            __syncthreads();
        }

        // ---- fold chunk scores into carried top-2 (regs + shfl only)
        const int cbase = codeBase + wc * 64;
        const float nrm0 = norms_s[cbase + lc];
        const float nrm1 = norms_s[cbase + 16 + lc];
        const float nrm2 = norms_s[cbase + 32 + lc];
        const float nrm3 = norms_s[cbase + 48 + lc];
        #pragma unroll
        for (int m = 0; m < 4; ++m) {
            #pragma unroll
            for (int r = 0; r < 4; ++r) {
                float s0 = fmaf(-2.f, acc[m][0][r], nrm0);
                float s1 = fmaf(-2.f, acc[m][1][r], nrm1);
                float s2 = fmaf(-2.f, acc[m][2][r], nrm2);
                float s3 = fmaf(-2.f, acc[m][3][r], nrm3);
                float m1 = s0, m2 = INFINITY;
                int   i1 = cbase + lc;
                if (s1 < m1) { m2 = m1; m1 = s1; i1 = cbase + 16 + lc; } else m2 = fminf(m2, s1);
                if (s2 < m1) { m2 = m1; m1 = s2; i1 = cbase + 32 + lc; } else m2 = fminf(m2, s2);
                if (s3 < m1) { m2 = m1; m1 = s3; i1 = cbase + 48 + lc; } else m2 = fminf(m2, s3);
                #pragma unroll
                for (int d = 1; d < 16; d <<= 1) {
                    float om1 = __shfl_xor(m1, d);
                    int   oi1 = __shfl_xor(i1, d);
                    float om2 = __shfl_xor(m2, d);
                    bool take = (om1 < m1) || (om1 == m1 && oi1 < i1);
                    float lose1 = take ? m1 : om1;
                    m2 = fminf(fminf(m2, om2), lose1);
                    m1 = take ? om1 : m1;
                    i1 = take ? oi1 : i1;
                }
                if (lc == (m * 4 + r)) {
                    bool take = (m1 < c_m1) || (m1 == c_m1 && i1 < c_i1);
                    float lose1 = take ? c_m1 : m1;
                    c_m2 = fminf(fminf(c_m2, m2), lose1);
                    c_m1 = take ? m1 : c_m1;
                    c_i1 = take ? i1 : c_i1;
                }
            }
        }
    }

    const int myrow = rowBase + wr * 64 + (lc >> 2) * 16 + lq * 4 + (lc & 3);
    const int quarter = half * 2 + wc;
    st_m1[quarter * ROWS + myrow] = c_m1;
    st_m2[quarter * ROWS + myrow] = c_m2;
    st_i1[quarter * ROWS + myrow] = c_i1;
}

// -------------------------------------------------------------------------
// Fallback GEMM (round-5 reg-staged, in-loop A conversion) — used only if
// ws_size is too small for preconverted residuals. Proven correct.
__global__ __launch_bounds__(256, 2)
void rvq_gemm_fallback_kernel(const float* __restrict__ src,
                              const unsigned short* __restrict__ cbh,
                              const unsigned short* __restrict__ cbl,
                              const float* __restrict__ norms_s,
                              float* __restrict__ st_m1,
                              float* __restrict__ st_m2,
                              int* __restrict__ st_i1)
{
    __shared__ char lds[32768];
    char* AhiB = lds;
    char* AloB = lds + 8192;
    char* BhiB = lds + 16384;
    char* BloB = lds + 24576;

    const int tid  = threadIdx.x;
    const int lane = tid & 63;
    const int lc   = lane & 15;
    const int lq   = lane >> 4;
    const int wv   = tid >> 6;
    const int wr   = wv >> 1;
    const int wc   = wv & 1;
    const int rowBase = blockIdx.x * 128;
    const int half = blockIdx.y;

    float c_m1 = INFINITY, c_m2 = INFINITY;
    int   c_i1 = 0;

    const int arow  = tid >> 1;
    const int ahalf = tid & 1;

    for (int chunk = 0; chunk < 4; ++chunk) {
        const int codeBase = half * 512 + chunk * 128;
        f32x4 acc[4][4];
        #pragma unroll
        for (int m = 0; m < 4; ++m)
            #pragma unroll
            for (int n = 0; n < 4; ++n) acc[m][n] = (f32x4){0.f, 0.f, 0.f, 0.f};

        for (int kt = 0; kt < D_ / 32; ++kt) {
            __syncthreads();
            {
                const float* ap = src + (size_t)(rowBase + arow) * D_ + kt * 32 + ahalf * 16;
                float fv[16];
                *(float4*)&fv[0]  = ((const float4*)ap)[0];
                *(float4*)&fv[4]  = ((const float4*)ap)[1];
                *(float4*)&fv[8]  = ((const float4*)ap)[2];
                *(float4*)&fv[12] = ((const float4*)ap)[3];
                bf16x8 H0, H1, L0, L1;
                #pragma unroll
                for (int j = 0; j < 8; ++j) {
                    unsigned short h0 = bf16rn(fv[j]);
                    H0[j] = (short)h0;
                    L0[j] = (short)bf16rn(fv[j] - bf16f(h0));
                    unsigned short h1 = bf16rn(fv[j + 8]);
                    H1[j] = (short)h1;
                    L1[j] = (short)bf16rn(fv[j + 8] - bf16f(h1));
                }
                const int q0 = ahalf * 2;
                *(bf16x8*)(AhiB + swzoff(arow, q0))     = H0;
                *(bf16x8*)(AhiB + swzoff(arow, q0 + 1)) = H1;
                *(bf16x8*)(AloB + swzoff(arow, q0))     = L0;
                *(bf16x8*)(AloB + swzoff(arow, q0 + 1)) = L1;
            }
            {
                const size_t boff = (size_t)(codeBase + arow) * D_ + kt * 32 + ahalf * 16;
                bf16x8 bh0 = *(const bf16x8*)(cbh + boff);
                bf16x8 bh1 = *(const bf16x8*)(cbh + boff + 8);
                bf16x8 bl0 = *(const bf16x8*)(cbl + boff);
                bf16x8 bl1 = *(const bf16x8*)(cbl + boff + 8);
                const int q0 = ahalf * 2;
                *(bf16x8*)(BhiB + swzoff(arow, q0))     = bh0;
                *(bf16x8*)(BhiB + swzoff(arow, q0 + 1)) = bh1;
                *(bf16x8*)(BloB + swzoff(arow, q0))     = bl0;
                *(bf16x8*)(BloB + swzoff(arow, q0 + 1)) = bl1;
            }
            __syncthreads();
            bf16x8 ah[4], al[4], bh[4], bl[4];
            #pragma unroll
            for (int m = 0; m < 4; ++m) {
                const int r = wr * 64 + m * 16 + lc;
                ah[m] = *(const bf16x8*)(AhiB + swzoff(r, lq));
                al[m] = *(const bf16x8*)(AloB + swzoff(r, lq));
            }
            #pragma unroll
            for (int n = 0; n < 4; ++n) {
                const int c = wc * 64 + n * 16 + lc;
                bh[n] = *(const bf16x8*)(BhiB + swzoff(c, lq));
                bl[n] = *(const bf16x8*)(BloB + swzoff(c, lq));
            }
            #pragma unroll
            for (int m = 0; m < 4; ++m)
                #pragma unroll
                for (int n = 0; n < 4; ++n) {
                    acc[m][n] = __builtin_amdgcn_mfma_f32_16x16x32_bf16(ah[m], bh[n], acc[m][n], 0, 0, 0);
                    acc[m][n] = __builtin_amdgcn_mfma_f32_16x16x32_bf16(ah[m], bl[n], acc[m][n], 0, 0, 0);
                    acc[m][n] = __builtin_amdgcn_mfma_f32_16x16x32_bf16(al[m], bh[n], acc[m][n], 0, 0, 0);
                }
        }

        const int cbase = codeBase + wc * 64;
        const float nrm0 = norms_s[cbase + lc];
        const float nrm1 = norms_s[cbase + 16 + lc];
        const float nrm2 = norms_s[cbase + 32 + lc];
        const float nrm3 = norms_s[cbase + 48 + lc];
        #pragma unroll
        for (int m = 0; m < 4; ++m) {
            #pragma unroll
            for (int r = 0; r < 4; ++r) {
                float s0 = fmaf(-2.f, acc[m][0][r], nrm0);
                float s1 = fmaf(-2.f, acc[m][1][r], nrm1);
                float s2 = fmaf(-2.f, acc[m][2][r], nrm2);
                float s3 = fmaf(-2.f, acc[m][3][r], nrm3);
                float m1 = s0, m2 = INFINITY;
                int   i1 = cbase + lc;
                if (s1 < m1) { m2 = m1; m1 = s1; i1 = cbase + 16 + lc; } else m2 = fminf(m2, s1);
                if (s2 < m1) { m2 = m1; m1 = s2; i1 = cbase + 32 + lc; } else m2 = fminf(m2, s2);
                if (s3 < m1) { m2 = m1; m1 = s3; i1 = cbase + 48 + lc; } else m2 = fminf(m2, s3);
                #pragma unroll
                for (int d = 1; d < 16; d <<= 1) {
                    float om1 = __shfl_xor(m1, d);
                    int   oi1 = __shfl_xor(i1, d);
                    float om2 = __shfl_xor(m2, d);
                    bool take = (om1 < m1) || (om1 == m1 && oi1 < i1);
                    float lose1 = take ? m1 : om1;
                    m2 = fminf(fminf(m2, om2), lose1);
                    m1 = take ? om1 : m1;
                    i1 = take ? oi1 : i1;
                }
                if (lc == (m * 4 + r)) {
                    bool take = (m1 < c_m1) || (m1 == c_m1 && i1 < c_i1);
                    float lose1 = take ? c_m1 : m1;
                    c_m2 = fminf(fminf(c_m2, m2), lose1);
                    c_m1 = take ? m1 : c_m1;
                    c_i1 = take ? i1 : c_i1;
                }
            }
        }
    }

    const int myrow = rowBase + wr * 64 + (lc >> 2) * 16 + lq * 4 + (lc & 3);
    const int quarter = half * 2 + wc;
    st_m1[quarter * ROWS + myrow] = c_m1;
    st_m2[quarter * ROWS + myrow] = c_m2;
    st_i1[quarter * ROWS + myrow] = c_i1;
}

// -------------------------------------------------------------------------
// merge 4 quarters -> final idx; near-tie rows appended to compact rescue list
__global__ __launch_bounds__(256)
void merge_kernel(const float* __restrict__ st_m1, const float* __restrict__ st_m2,
                  const int* __restrict__ st_i1,
                  int* __restrict__ idx_i, float* __restrict__ idx_f,
                  int* __restrict__ list, int* __restrict__ nflag, int q) {
    const int row = blockIdx.x * 256 + threadIdx.x;
    float m1 = st_m1[row], m2 = st_m2[row];
    int   i1 = st_i1[row];
    #pragma unroll
    for (int qt = 1; qt < 4; ++qt) {
        float om1 = st_m1[qt * ROWS + row];
        float om2 = st_m2[qt * ROWS + row];
        int   oi1 = st_i1[qt * ROWS + row];
        if (om1 < m1) { m2 = fminf(m1, om2); m1 = om1; i1 = oi1; }
        else          { m2 = fminf(m2, om1); }
    }
    idx_i[row] = i1;
    idx_f[(size_t)row * Q_ + q] = (float)i1;
    if (m2 - m1 < TAU) {
        const int p = atomicAdd(nflag, 1);
        list[p] = row;
    }
}

// -------------------------------------------------------------------------
// Exact-f32 re-argmin for near-tie rows, compact-list driven.
__global__ __launch_bounds__(256)
void rescue_kernel(const float* __restrict__ src, const float* __restrict__ cb,
                   const float* __restrict__ norms_s,
                   const int* __restrict__ list, const int* __restrict__ nflag_p,
                   int* __restrict__ idx_i, float* __restrict__ idx_f, int q)
{
    __shared__ float As[D_][RCH];      // residual rows, [k][row] (16 KB)
    __shared__ int   rows_s[RCH];
    __shared__ float wm[4][RCH];
    __shared__ int   wi[4][RCH];
    const int nflag = nflag_p[0];
    const int tid = threadIdx.x;

    for (int chunk = blockIdx.x; chunk * RCH < nflag; chunk += gridDim.x) {
        __syncthreads();
        if (tid < RCH) {
            const int li = chunk * RCH + tid;
            rows_s[tid] = list[li < nflag ? li : nflag - 1];   // pad = dup last
        }
        __syncthreads();
        #pragma unroll
        for (int i = 0; i < 4; ++i) {
            const int v  = tid + 256 * i;
            const int r  = v >> 7;
            const int k4 = (v & 127) * 4;
            float4 f = *(const float4*)(src + (size_t)rows_s[r] * D_ + k4);
            As[k4 + 0][r] = f.x; As[k4 + 1][r] = f.y;
            As[k4 + 2][r] = f.z; As[k4 + 3][r] = f.w;
        }
        __syncthreads();

        float acc[4][RCH];
        #pragma unroll
        for (int j = 0; j < 4; ++j)
            #pragma unroll
            for (int r = 0; r < RCH; ++r) acc[j][r] = 0.f;

        for (int k = 0; k < D_; k += 4) {
            float4 bq[4];
            #pragma unroll
            for (int j = 0; j < 4; ++j)
                bq[j] = *(const float4*)(cb + (size_t)(tid + 256 * j) * D_ + k);
            const float* bp = (const float*)&bq[0];
            const float* ap = &As[k][0];
            #pragma unroll
            for (int e = 0; e < 4; ++e)
                #pragma unroll
                for (int r = 0; r < RCH; ++r) {
                    const float a = ap[e * RCH + r];
                    #pragma unroll
                    for (int j = 0; j < 4; ++j)
                        acc[j][r] = fmaf(bp[j * 4 + e], a, acc[j][r]);
                }
        }

        float m1[RCH]; int i1[RCH];
        #pragma unroll
        for (int r = 0; r < RCH; ++r) { m1[r] = INFINITY; i1[r] = 0; }
        #pragma unroll
        for (int j = 0; j < 4; ++j) {
            const int c = tid + 256 * j;
            const float nr = norms_s[c];
            #pragma unroll
            for (int r = 0; r < RCH; ++r) {
                const float s = fmaf(-2.f, acc[j][r], nr);
                if (s < m1[r]) { m1[r] = s; i1[r] = c; }
            }
        }
        #pragma unroll
        for (int d = 1; d < 64; d <<= 1)
            #pragma unroll
            for (int r = 0; r < RCH; ++r) {
                const float om = __shfl_xor(m1[r], d);
                const int   oi = __shfl_xor(i1[r], d);
                if (om < m1[r] || (om == m1[r] && oi < i1[r])) { m1[r] = om; i1[r] = oi; }
            }
        if ((tid & 63) == 0)
            #pragma unroll
            for (int r = 0; r < RCH; ++r) { wm[tid >> 6][r] = m1[r]; wi[tid >> 6][r] = i1[r]; }
        __syncthreads();
        if (tid < RCH) {
            float bm = wm[0][tid]; int bi = wi[0][tid];
            #pragma unroll
            for (int w = 1; w < 4; ++w)
                if (wm[w][tid] < bm || (wm[w][tid] == bm && wi[w][tid] < bi)) {
                    bm = wm[w][tid]; bi = wi[w][tid];
                }
            const int li = chunk * RCH + tid;
            if (li < nflag) {
                const int row = rows_s[tid];
                idx_i[row] = bi;
                idx_f[(size_t)row * Q_ + q] = (float)bi;
            }
        }
    }
}

// -------------------------------------------------------------------------
// residual update: newres = res - cb[idx] (exact f32); loss; final qout.
// write_hl: also emit bf16 hi/lo of newres for next stage's GEMM A.
__global__ __launch_bounds__(256)
void update_kernel(const float* __restrict__ src, float* __restrict__ dst,
                   const float* __restrict__ x, const float* __restrict__ cb,
                   const int* __restrict__ idx_i, float* __restrict__ loss_out,
                   unsigned short* __restrict__ rhi, unsigned short* __restrict__ rlo,
                   int is_last, int write_hl) {
    __shared__ int ids[64];
    const int tid = threadIdx.x;
    const int rowBase = blockIdx.x * 64;
    if (tid < 64) ids[tid] = idx_i[rowBase + tid];
    __syncthreads();
    float lsum = 0.f;
    #pragma unroll 4
    for (int e4 = tid; e4 < 64 * D_ / 4; e4 += 256) {
        const int row  = e4 >> 7;
        const int d    = (e4 & 127) * 4;
        const int code = ids[row];
        const size_t off = (size_t)(rowBase + row) * D_ + d;
        float4 r = *(const float4*)(src + off);
        float4 e = *(const float4*)(cb + (size_t)code * D_ + d);
        float4 nr = make_float4(r.x - e.x, r.y - e.y, r.z - e.z, r.w - e.w);
        lsum += nr.x * nr.x + nr.y * nr.y + nr.z * nr.z + nr.w * nr.w;
        if (is_last) {
            float4 xv = *(const float4*)(x + off);
            *(float4*)(dst + off) = make_float4(xv.x - nr.x, xv.y - nr.y,
                                                xv.z - nr.z, xv.w - nr.w);
        } else {
            *(float4*)(dst + off) = nr;
        }
        if (write_hl) {
            ushort4 h, l;
            h.x = bf16rn(nr.x); l.x = bf16rn(nr.x - bf16f(h.x));
            h.y = bf16rn(nr.y); l.y = bf16rn(nr.y - bf16f(h.y));
            h.z = bf16rn(nr.z); l.z = bf16rn(nr.z - bf16f(h.z));
            h.w = bf16rn(nr.w); l.w = bf16rn(nr.w - bf16f(h.w));
            *(ushort4*)(rhi + off) = h;
            *(ushort4*)(rlo + off) = l;
        }
    }
    #pragma unroll
    for (int m = 1; m < 64; m <<= 1) lsum += __shfl_xor(lsum, m);
    if ((tid & 63) == 0)
        atomicAdd(loss_out, lsum * (1.0f / ((float)ROWS * (float)D_)));
}

// -------------------------------------------------------------------------
extern "C" void kernel_launch(void* const* d_in, const int* in_sizes, int n_in,
                              void* d_out, int out_size, void* d_ws, size_t ws_size,
                              hipStream_t stream) {
    const float* x  = (const float*)d_in[0];   // [B,N,D]
    const float* cb = (const float*)d_in[1];   // [Q,C,D]

    float* qout   = (float*)d_out;                                  // doubles as residual
    float* idx_f  = (float*)d_out + (size_t)ROWS * D_;              // [ROWS][Q_] as floats
    float* losses = idx_f + (size_t)ROWS * Q_;                      // [Q_]

    char* w = (char*)d_ws;
    unsigned short* cb_hi = (unsigned short*)w;                     // Q*C*D bf16 (8MB)
    unsigned short* cb_lo = cb_hi + (size_t)Q_ * C_ * D_;           // 8MB
    float* norms = (float*)(cb_lo + (size_t)Q_ * C_ * D_);          // Q*C
    float* st_m1 = norms + Q_ * C_;                                 // 4*ROWS
    float* st_m2 = st_m1 + 4 * ROWS;
    int*   st_i1 = (int*)(st_m2 + 4 * ROWS);
    int*   idx_i = st_i1 + 4 * ROWS;                                // ROWS
    int*   list  = idx_i + ROWS;                                    // ROWS
    int*   nflag = list + ROWS;                                     // 64 (aligned pad)
    unsigned short* res_hi = (unsigned short*)(nflag + 64);         // ROWS*D (32MB)
    unsigned short* res_lo = res_hi + (size_t)ROWS * D_;            // 32MB

    const size_t need = (size_t)((char*)(res_lo + (size_t)ROWS * D_) - w);
    const int preconv = (ws_size >= need) ? 1 : 0;

    hipMemsetAsync(losses, 0, Q_ * sizeof(float), stream);
    cb_convert_kernel<<<Q_ * C_ * D_ / 1024, 256, 0, stream>>>(cb, cb_hi, cb_lo);
    code_norms_kernel<<<Q_ * C_ / 4, 256, 0, stream>>>(cb, norms);
    if (preconv)   // stage-0 A = x
        cb_convert_kernel<<<(int)((size_t)ROWS * D_ / 1024), 256, 0, stream>>>(x, res_hi, res_lo);

    for (int q = 0; q < Q_; ++q) {
        const float* src = (q == 0) ? x : qout;
        const float* cb_s = cb + (size_t)q * C_ * D_;
        if (preconv)
            rvq_gemm_pipe_kernel<<<dim3(ROWS / 128, 2), 256, 0, stream>>>(
                res_hi, res_lo,
                cb_hi + (size_t)q * C_ * D_, cb_lo + (size_t)q * C_ * D_,
                norms + (size_t)q * C_, st_m1, st_m2, st_i1);
        else
            rvq_gemm_fallback_kernel<<<dim3(ROWS / 128, 2), 256, 0, stream>>>(
                src, cb_hi + (size_t)q * C_ * D_, cb_lo + (size_t)q * C_ * D_,
                norms + (size_t)q * C_, st_m1, st_m2, st_i1);
        hipMemsetAsync(nflag, 0, sizeof(int), stream);
        merge_kernel<<<ROWS / 256, 256, 0, stream>>>(
            st_m1, st_m2, st_i1, idx_i, idx_f, list, nflag, q);
        rescue_kernel<<<256, 256, 0, stream>>>(
            src, cb_s, norms + (size_t)q * C_, list, nflag, idx_i, idx_f, q);
        update_kernel<<<ROWS / 64, 256, 0, stream>>>(
            src, qout, x, cb_s, idx_i, losses + q, res_hi, res_lo,
            (q == Q_ - 1) ? 1 : 0, (preconv && q < Q_ - 1) ? 1 : 0);
    }
}

// Round 7
// 2014.727 us; speedup vs baseline: 1.0244x; 1.0062x over previous
//
#include <hip/hip_runtime.h>
#include <math.h>

// Problem constants (ResidualVQ: B=8, N=4096, D=512, C=1024, Q=8)
#define B_   8
#define N_   4096
#define D_   512
#define C_   1024
#define Q_   8
#define ROWS (B_ * N_)   // 32768 token rows

#define TAU  0.1f        // rescue margin; approx-score error bound ~5e-4
#define RCH  8           // rows per rescue chunk

typedef __attribute__((ext_vector_type(8))) short bf16x8;
typedef __attribute__((ext_vector_type(4))) float f32x4;

// round-to-nearest-even f32 -> bf16 (bits)
__device__ __forceinline__ unsigned short bf16rn(float f) {
    unsigned int u = __builtin_bit_cast(unsigned int, f);
    return (unsigned short)((u + 0x7fffu + ((u >> 16) & 1u)) >> 16);
}
__device__ __forceinline__ float bf16f(unsigned short h) {
    unsigned int u = ((unsigned int)h) << 16;
    return __builtin_bit_cast(float, u);
}
// LDS byte offset for tile [row][32 bf16], XOR-swizzled (<=2-way conflicts)
__device__ __forceinline__ int swzoff(int row, int q) {
    return row * 64 + ((q ^ ((row >> 1) & 3)) << 4);
}
// async global->LDS, 16B per lane. LDS dest wave-uniform+lane*16; global src per-lane.
__device__ __forceinline__ void gload16(const void* g, void* l) {
    __builtin_amdgcn_global_load_lds(
        (const __attribute__((address_space(1))) void*)g,
        (__attribute__((address_space(3))) void*)l, 16, 0, 0);
}

// -------------------------------------------------------------------------
// f32 -> hi/lo bf16 (codebooks once per call; x at stage 0)
__global__ __launch_bounds__(256)
void cb_convert_kernel(const float* __restrict__ cb,
                       unsigned short* __restrict__ hi,
                       unsigned short* __restrict__ lo) {
    const int i4 = blockIdx.x * 256 + threadIdx.x;      // float4 index
    float4 v = ((const float4*)cb)[i4];
    ushort4 h, l;
    h.x = bf16rn(v.x); l.x = bf16rn(v.x - bf16f(h.x));
    h.y = bf16rn(v.y); l.y = bf16rn(v.y - bf16f(h.y));
    h.z = bf16rn(v.z); l.z = bf16rn(v.z - bf16f(h.z));
    h.w = bf16rn(v.w); l.w = bf16rn(v.w - bf16f(h.w));
    ((ushort4*)hi)[i4] = h;
    ((ushort4*)lo)[i4] = l;
}

// ||e||^2 for every code of every stage (exact f32)
__global__ __launch_bounds__(256)
void code_norms_kernel(const float* __restrict__ cb, float* __restrict__ norms) {
    const int code = blockIdx.x * 4 + (threadIdx.x >> 6);
    const int lane = threadIdx.x & 63;
    const float* p = cb + (size_t)code * D_;
    float s = 0.f;
    #pragma unroll
    for (int d = lane * 4; d < D_; d += 256) {
        float4 v = *(const float4*)(p + d);
        s += v.x * v.x + v.y * v.y + v.z * v.z + v.w * v.w;
    }
    #pragma unroll
    for (int m = 1; m < 64; m <<= 1) s += __shfl_xor(s, m);
    if (lane == 0) norms[code] = s;
}

// -------------------------------------------------------------------------
// Pipelined split-bf16 MFMA scoring GEMM — counted-vmcnt schedule (T4):
// per step: STAGE(t+1) -> s_waitcnt vmcnt(8) (tile-t loads done, tile-t+1
// stays IN FLIGHT across the barrier) -> raw s_barrier -> ds_read ->
// lgkmcnt(0)+sched_barrier -> raw s_barrier -> 48 MFMA. Never vmcnt(0)
// in the main loop. Grid 512 1-D: x=bid&255, half=bid>>8 so the two
// C-half blocks of the same rows are bid and bid+256 (same XCD mod 8).
__global__ __launch_bounds__(256, 2)
void rvq_gemm_pipe_kernel(const unsigned short* __restrict__ ahi, // residual hi [ROWS][D_]
                          const unsigned short* __restrict__ alo, // residual lo
                          const unsigned short* __restrict__ cbh, // stage cb hi [C_][D_]
                          const unsigned short* __restrict__ cbl, // stage cb lo
                          const float* __restrict__ norms_s,      // [C_]
                          float* __restrict__ st_m1,              // [4][ROWS]
                          float* __restrict__ st_m2,              // [4][ROWS]
                          int* __restrict__ st_i1)                // [4][ROWS]
{
    __shared__ char lds[65536];        // [db:2][buf:4(Ahi,Alo,Bhi,Blo)][8192]

    const int tid  = threadIdx.x;
    const int lane = tid & 63;
    const int lc   = lane & 15;        // code/row lane within frag
    const int lq   = lane >> 4;        // k-chunk of fragment
    const int wv   = tid >> 6;
    const int wr   = wv >> 1;          // wave row-half (0..1)
    const int wc   = wv & 1;           // wave code-half (0..1)
    const int rowBase = (blockIdx.x & 255) * 128;
    const int half = blockIdx.x >> 8;

    // ---- staging role (wave wv owns buffer wv)
    const unsigned short* ssrc =
        (wv == 0) ? ahi : (wv == 1) ? alo : (wv == 2) ? cbh : cbl;
    const bool isA = (wv < 2);
    const int srow = lane >> 2;                      // 0..15 (row within 1KB issue)
    const int qsw  = (lane & 3) ^ ((srow >> 1) & 3); // inverse-swizzled k-slot
    char* const sbuf = lds + wv * 8192;

    auto STAGE = [&](int db, int c, int kt) {
        const int grow0 = isA ? rowBase : (half * 512 + c * 128);
        const unsigned short* p0 =
            ssrc + (size_t)(grow0 + srow) * D_ + kt * 32 + qsw * 8;
        char* lb = sbuf + db * 32768;
        #pragma unroll
        for (int i = 0; i < 8; ++i)                 // 8 x (64 lanes x 16B) = 8KB
            gload16(p0 + (size_t)i * 16 * D_, lb + i * 1024);
    };

    float c_m1 = INFINITY, c_m2 = INFINITY;
    int   c_i1 = 0;

    STAGE(0, 0, 0);    // 8 loads in flight; awaited by vmcnt(8) at t=0

    for (int chunk = 0; chunk < 4; ++chunk) {
        const int codeBase = half * 512 + chunk * 128;
        f32x4 acc[4][4];
        #pragma unroll
        for (int m = 0; m < 4; ++m)
            #pragma unroll
            for (int n = 0; n < 4; ++n) acc[m][n] = (f32x4){0.f, 0.f, 0.f, 0.f};

        for (int kt = 0; kt < 16; ++kt) {
            const int t  = chunk * 16 + kt;
            const int db = t & 1;
            // prefetch next tile into the other buffer, then wait for the
            // OLDEST 8 loads only (= tile t). Tile t+1 stays in flight.
            if (t < 63) {
                STAGE(db ^ 1, (t + 1) >> 4, (t + 1) & 15);
                asm volatile("s_waitcnt vmcnt(8)" ::: "memory");
            } else {
                asm volatile("s_waitcnt vmcnt(0)" ::: "memory");
            }
            __builtin_amdgcn_s_barrier();           // all waves: tile t landed
            asm volatile("" ::: "memory");          // fence: ds_reads stay below

            char* base = lds + db * 32768;
            char* AhiB = base;
            char* AloB = base + 8192;
            char* BhiB = base + 16384;
            char* BloB = base + 24576;

            bf16x8 ah[4], al[4], bh[4], bl[4];
            #pragma unroll
            for (int m = 0; m < 4; ++m) {
                const int r = wr * 64 + m * 16 + lc;
                ah[m] = *(const bf16x8*)(AhiB + swzoff(r, lq));
                al[m] = *(const bf16x8*)(AloB + swzoff(r, lq));
            }
            #pragma unroll
            for (int n = 0; n < 4; ++n) {
                const int c = wc * 64 + n * 16 + lc;
                bh[n] = *(const bf16x8*)(BhiB + swzoff(c, lq));
                bl[n] = *(const bf16x8*)(BloB + swzoff(c, lq));
            }
            // all ds_reads of buf[db] complete before anyone may overwrite it
            asm volatile("s_waitcnt lgkmcnt(0)" ::: "memory");
            __builtin_amdgcn_sched_barrier(0);
            __builtin_amdgcn_s_barrier();

            #pragma unroll
            for (int m = 0; m < 4; ++m)
                #pragma unroll
                for (int n = 0; n < 4; ++n) {
                    acc[m][n] = __builtin_amdgcn_mfma_f32_16x16x32_bf16(ah[m], bh[n], acc[m][n], 0, 0, 0);
                    acc[m][n] = __builtin_amdgcn_mfma_f32_16x16x32_bf16(ah[m], bl[n], acc[m][n], 0, 0, 0);
                    acc[m][n] = __builtin_amdgcn_mfma_f32_16x16x32_bf16(al[m], bh[n], acc[m][n], 0, 0, 0);
                }
        }

        // ---- fold chunk scores into carried top-2 (regs + shfl only)
        const int cbase = codeBase + wc * 64;
        const float nrm0 = norms_s[cbase + lc];
        const float nrm1 = norms_s[cbase + 16 + lc];
        const float nrm2 = norms_s[cbase + 32 + lc];
        const float nrm3 = norms_s[cbase + 48 + lc];
        #pragma unroll
        for (int m = 0; m < 4; ++m) {
            #pragma unroll
            for (int r = 0; r < 4; ++r) {
                float s0 = fmaf(-2.f, acc[m][0][r], nrm0);
                float s1 = fmaf(-2.f, acc[m][1][r], nrm1);
                float s2 = fmaf(-2.f, acc[m][2][r], nrm2);
                float s3 = fmaf(-2.f, acc[m][3][r], nrm3);
                float m1 = s0, m2 = INFINITY;
                int   i1 = cbase + lc;
                if (s1 < m1) { m2 = m1; m1 = s1; i1 = cbase + 16 + lc; } else m2 = fminf(m2, s1);
                if (s2 < m1) { m2 = m1; m1 = s2; i1 = cbase + 32 + lc; } else m2 = fminf(m2, s2);
                if (s3 < m1) { m2 = m1; m1 = s3; i1 = cbase + 48 + lc; } else m2 = fminf(m2, s3);
                #pragma unroll
                for (int d = 1; d < 16; d <<= 1) {
                    float om1 = __shfl_xor(m1, d);
                    int   oi1 = __shfl_xor(i1, d);
                    float om2 = __shfl_xor(m2, d);
                    bool take = (om1 < m1) || (om1 == m1 && oi1 < i1);
                    float lose1 = take ? m1 : om1;
                    m2 = fminf(fminf(m2, om2), lose1);
                    m1 = take ? om1 : m1;
                    i1 = take ? oi1 : i1;
                }
                if (lc == (m * 4 + r)) {
                    bool take = (m1 < c_m1) || (m1 == c_m1 && i1 < c_i1);
                    float lose1 = take ? c_m1 : m1;
                    c_m2 = fminf(fminf(c_m2, m2), lose1);
                    c_m1 = take ? m1 : c_m1;
                    c_i1 = take ? i1 : c_i1;
                }
            }
        }
    }

    const int myrow = rowBase + wr * 64 + (lc >> 2) * 16 + lq * 4 + (lc & 3);
    const int quarter = half * 2 + wc;
    st_m1[quarter * ROWS + myrow] = c_m1;
    st_m2[quarter * ROWS + myrow] = c_m2;
    st_i1[quarter * ROWS + myrow] = c_i1;
}

// -------------------------------------------------------------------------
// Fallback GEMM (reg-staged, in-loop A conversion) — used only if ws_size is
// too small for preconverted residuals. Proven correct (round 4/5).
__global__ __launch_bounds__(256, 2)
void rvq_gemm_fallback_kernel(const float* __restrict__ src,
                              const unsigned short* __restrict__ cbh,
                              const unsigned short* __restrict__ cbl,
                              const float* __restrict__ norms_s,
                              float* __restrict__ st_m1,
                              float* __restrict__ st_m2,
                              int* __restrict__ st_i1)
{
    __shared__ char lds[32768];
    char* AhiB = lds;
    char* AloB = lds + 8192;
    char* BhiB = lds + 16384;
    char* BloB = lds + 24576;

    const int tid  = threadIdx.x;
    const int lane = tid & 63;
    const int lc   = lane & 15;
    const int lq   = lane >> 4;
    const int wv   = tid >> 6;
    const int wr   = wv >> 1;
    const int wc   = wv & 1;
    const int rowBase = blockIdx.x * 128;
    const int half = blockIdx.y;

    float c_m1 = INFINITY, c_m2 = INFINITY;
    int   c_i1 = 0;

    const int arow  = tid >> 1;
    const int ahalf = tid & 1;

    for (int chunk = 0; chunk < 4; ++chunk) {
        const int codeBase = half * 512 + chunk * 128;
        f32x4 acc[4][4];
        #pragma unroll
        for (int m = 0; m < 4; ++m)
            #pragma unroll
            for (int n = 0; n < 4; ++n) acc[m][n] = (f32x4){0.f, 0.f, 0.f, 0.f};

        for (int kt = 0; kt < D_ / 32; ++kt) {
            __syncthreads();
            {
                const float* ap = src + (size_t)(rowBase + arow) * D_ + kt * 32 + ahalf * 16;
                float fv[16];
                *(float4*)&fv[0]  = ((const float4*)ap)[0];
                *(float4*)&fv[4]  = ((const float4*)ap)[1];
                *(float4*)&fv[8]  = ((const float4*)ap)[2];
                *(float4*)&fv[12] = ((const float4*)ap)[3];
                bf16x8 H0, H1, L0, L1;
                #pragma unroll
                for (int j = 0; j < 8; ++j) {
                    unsigned short h0 = bf16rn(fv[j]);
                    H0[j] = (short)h0;
                    L0[j] = (short)bf16rn(fv[j] - bf16f(h0));
                    unsigned short h1 = bf16rn(fv[j + 8]);
                    H1[j] = (short)h1;
                    L1[j] = (short)bf16rn(fv[j + 8] - bf16f(h1));
                }
                const int q0 = ahalf * 2;
                *(bf16x8*)(AhiB + swzoff(arow, q0))     = H0;
                *(bf16x8*)(AhiB + swzoff(arow, q0 + 1)) = H1;
                *(bf16x8*)(AloB + swzoff(arow, q0))     = L0;
                *(bf16x8*)(AloB + swzoff(arow, q0 + 1)) = L1;
            }
            {
                const size_t boff = (size_t)(codeBase + arow) * D_ + kt * 32 + ahalf * 16;
                bf16x8 bh0 = *(const bf16x8*)(cbh + boff);
                bf16x8 bh1 = *(const bf16x8*)(cbh + boff + 8);
                bf16x8 bl0 = *(const bf16x8*)(cbl + boff);
                bf16x8 bl1 = *(const bf16x8*)(cbl + boff + 8);
                const int q0 = ahalf * 2;
                *(bf16x8*)(BhiB + swzoff(arow, q0))     = bh0;
                *(bf16x8*)(BhiB + swzoff(arow, q0 + 1)) = bh1;
                *(bf16x8*)(BloB + swzoff(arow, q0))     = bl0;
                *(bf16x8*)(BloB + swzoff(arow, q0 + 1)) = bl1;
            }
            __syncthreads();
            bf16x8 ah[4], al[4], bh[4], bl[4];
            #pragma unroll
            for (int m = 0; m < 4; ++m) {
                const int r = wr * 64 + m * 16 + lc;
                ah[m] = *(const bf16x8*)(AhiB + swzoff(r, lq));
                al[m] = *(const bf16x8*)(AloB + swzoff(r, lq));
            }
            #pragma unroll
            for (int n = 0; n < 4; ++n) {
                const int c = wc * 64 + n * 16 + lc;
                bh[n] = *(const bf16x8*)(BhiB + swzoff(c, lq));
                bl[n] = *(const bf16x8*)(BloB + swzoff(c, lq));
            }
            #pragma unroll
            for (int m = 0; m < 4; ++m)
                #pragma unroll
                for (int n = 0; n < 4; ++n) {
                    acc[m][n] = __builtin_amdgcn_mfma_f32_16x16x32_bf16(ah[m], bh[n], acc[m][n], 0, 0, 0);
                    acc[m][n] = __builtin_amdgcn_mfma_f32_16x16x32_bf16(ah[m], bl[n], acc[m][n], 0, 0, 0);
                    acc[m][n] = __builtin_amdgcn_mfma_f32_16x16x32_bf16(al[m], bh[n], acc[m][n], 0, 0, 0);
                }
        }

        const int cbase = codeBase + wc * 64;
        const float nrm0 = norms_s[cbase + lc];
        const float nrm1 = norms_s[cbase + 16 + lc];
        const float nrm2 = norms_s[cbase + 32 + lc];
        const float nrm3 = norms_s[cbase + 48 + lc];
        #pragma unroll
        for (int m = 0; m < 4; ++m) {
            #pragma unroll
            for (int r = 0; r < 4; ++r) {
                float s0 = fmaf(-2.f, acc[m][0][r], nrm0);
                float s1 = fmaf(-2.f, acc[m][1][r], nrm1);
                float s2 = fmaf(-2.f, acc[m][2][r], nrm2);
                float s3 = fmaf(-2.f, acc[m][3][r], nrm3);
                float m1 = s0, m2 = INFINITY;
                int   i1 = cbase + lc;
                if (s1 < m1) { m2 = m1; m1 = s1; i1 = cbase + 16 + lc; } else m2 = fminf(m2, s1);
                if (s2 < m1) { m2 = m1; m1 = s2; i1 = cbase + 32 + lc; } else m2 = fminf(m2, s2);
                if (s3 < m1) { m2 = m1; m1 = s3; i1 = cbase + 48 + lc; } else m2 = fminf(m2, s3);
                #pragma unroll
                for (int d = 1; d < 16; d <<= 1) {
                    float om1 = __shfl_xor(m1, d);
                    int   oi1 = __shfl_xor(i1, d);
                    float om2 = __shfl_xor(m2, d);
                    bool take = (om1 < m1) || (om1 == m1 && oi1 < i1);
                    float lose1 = take ? m1 : om1;
                    m2 = fminf(fminf(m2, om2), lose1);
                    m1 = take ? om1 : m1;
                    i1 = take ? oi1 : i1;
                }
                if (lc == (m * 4 + r)) {
                    bool take = (m1 < c_m1) || (m1 == c_m1 && i1 < c_i1);
                    float lose1 = take ? c_m1 : m1;
                    c_m2 = fminf(fminf(c_m2, m2), lose1);
                    c_m1 = take ? m1 : c_m1;
                    c_i1 = take ? i1 : c_i1;
                }
            }
        }
    }

    const int myrow = rowBase + wr * 64 + (lc >> 2) * 16 + lq * 4 + (lc & 3);
    const int quarter = half * 2 + wc;
    st_m1[quarter * ROWS + myrow] = c_m1;
    st_m2[quarter * ROWS + myrow] = c_m2;
    st_i1[quarter * ROWS + myrow] = c_i1;
}

// -------------------------------------------------------------------------
// merge 4 quarters -> final idx; near-tie rows appended to compact rescue list
__global__ __launch_bounds__(256)
void merge_kernel(const float* __restrict__ st_m1, const float* __restrict__ st_m2,
                  const int* __restrict__ st_i1,
                  int* __restrict__ idx_i, float* __restrict__ idx_f,
                  int* __restrict__ list, int* __restrict__ nflag, int q) {
    const int row = blockIdx.x * 256 + threadIdx.x;
    float m1 = st_m1[row], m2 = st_m2[row];
    int   i1 = st_i1[row];
    #pragma unroll
    for (int qt = 1; qt < 4; ++qt) {
        float om1 = st_m1[qt * ROWS + row];
        float om2 = st_m2[qt * ROWS + row];
        int   oi1 = st_i1[qt * ROWS + row];
        if (om1 < m1) { m2 = fminf(m1, om2); m1 = om1; i1 = oi1; }
        else          { m2 = fminf(m2, om1); }
    }
    idx_i[row] = i1;
    idx_f[(size_t)row * Q_ + q] = (float)i1;
    if (m2 - m1 < TAU) {
        const int p = atomicAdd(nflag, 1);
        list[p] = row;
    }
}

// -------------------------------------------------------------------------
// Exact-f32 re-argmin for near-tie rows, compact-list driven.
__global__ __launch_bounds__(256)
void rescue_kernel(const float* __restrict__ src, const float* __restrict__ cb,
                   const float* __restrict__ norms_s,
                   const int* __restrict__ list, const int* __restrict__ nflag_p,
                   int* __restrict__ idx_i, float* __restrict__ idx_f, int q)
{
    __shared__ float As[D_][RCH];      // residual rows, [k][row] (16 KB)
    __shared__ int   rows_s[RCH];
    __shared__ float wm[4][RCH];
    __shared__ int   wi[4][RCH];
    const int nflag = nflag_p[0];
    const int tid = threadIdx.x;

    for (int chunk = blockIdx.x; chunk * RCH < nflag; chunk += gridDim.x) {
        __syncthreads();
        if (tid < RCH) {
            const int li = chunk * RCH + tid;
            rows_s[tid] = list[li < nflag ? li : nflag - 1];   // pad = dup last
        }
        __syncthreads();
        #pragma unroll
        for (int i = 0; i < 4; ++i) {
            const int v  = tid + 256 * i;
            const int r  = v >> 7;
            const int k4 = (v & 127) * 4;
            float4 f = *(const float4*)(src + (size_t)rows_s[r] * D_ + k4);
            As[k4 + 0][r] = f.x; As[k4 + 1][r] = f.y;
            As[k4 + 2][r] = f.z; As[k4 + 3][r] = f.w;
        }
        __syncthreads();

        float acc[4][RCH];
        #pragma unroll
        for (int j = 0; j < 4; ++j)
            #pragma unroll
            for (int r = 0; r < RCH; ++r) acc[j][r] = 0.f;

        for (int k = 0; k < D_; k += 4) {
            float4 bq[4];
            #pragma unroll
            for (int j = 0; j < 4; ++j)
                bq[j] = *(const float4*)(cb + (size_t)(tid + 256 * j) * D_ + k);
            const float* bp = (const float*)&bq[0];
            const float* ap = &As[k][0];
            #pragma unroll
            for (int e = 0; e < 4; ++e)
                #pragma unroll
                for (int r = 0; r < RCH; ++r) {
                    const float a = ap[e * RCH + r];
                    #pragma unroll
                    for (int j = 0; j < 4; ++j)
                        acc[j][r] = fmaf(bp[j * 4 + e], a, acc[j][r]);
                }
        }

        float m1[RCH]; int i1[RCH];
        #pragma unroll
        for (int r = 0; r < RCH; ++r) { m1[r] = INFINITY; i1[r] = 0; }
        #pragma unroll
        for (int j = 0; j < 4; ++j) {
            const int c = tid + 256 * j;
            const float nr = norms_s[c];
            #pragma unroll
            for (int r = 0; r < RCH; ++r) {
                const float s = fmaf(-2.f, acc[j][r], nr);
                if (s < m1[r]) { m1[r] = s; i1[r] = c; }
            }
        }
        #pragma unroll
        for (int d = 1; d < 64; d <<= 1)
            #pragma unroll
            for (int r = 0; r < RCH; ++r) {
                const float om = __shfl_xor(m1[r], d);
                const int   oi = __shfl_xor(i1[r], d);
                if (om < m1[r] || (om == m1[r] && oi < i1[r])) { m1[r] = om; i1[r] = oi; }
            }
        if ((tid & 63) == 0)
            #pragma unroll
            for (int r = 0; r < RCH; ++r) { wm[tid >> 6][r] = m1[r]; wi[tid >> 6][r] = i1[r]; }
        __syncthreads();
        if (tid < RCH) {
            float bm = wm[0][tid]; int bi = wi[0][tid];
            #pragma unroll
            for (int w = 1; w < 4; ++w)
                if (wm[w][tid] < bm || (wm[w][tid] == bm && wi[w][tid] < bi)) {
                    bm = wm[w][tid]; bi = wi[w][tid];
                }
            const int li = chunk * RCH + tid;
            if (li < nflag) {
                const int row = rows_s[tid];
                idx_i[row] = bi;
                idx_f[(size_t)row * Q_ + q] = (float)bi;
            }
        }
    }
}

// -------------------------------------------------------------------------
// residual update: newres = res - cb[idx] (exact f32); loss; final qout.
// write_hl: also emit bf16 hi/lo of newres for next stage's GEMM A.
__global__ __launch_bounds__(256)
void update_kernel(const float* __restrict__ src, float* __restrict__ dst,
                   const float* __restrict__ x, const float* __restrict__ cb,
                   const int* __restrict__ idx_i, float* __restrict__ loss_out,
                   unsigned short* __restrict__ rhi, unsigned short* __restrict__ rlo,
                   int is_last, int write_hl) {
    __shared__ int ids[64];
    const int tid = threadIdx.x;
    const int rowBase = blockIdx.x * 64;
    if (tid < 64) ids[tid] = idx_i[rowBase + tid];
    __syncthreads();
    float lsum = 0.f;
    #pragma unroll 4
    for (int e4 = tid; e4 < 64 * D_ / 4; e4 += 256) {
        const int row  = e4 >> 7;
        const int d    = (e4 & 127) * 4;
        const int code = ids[row];
        const size_t off = (size_t)(rowBase + row) * D_ + d;
        float4 r = *(const float4*)(src + off);
        float4 e = *(const float4*)(cb + (size_t)code * D_ + d);
        float4 nr = make_float4(r.x - e.x, r.y - e.y, r.z - e.z, r.w - e.w);
        lsum += nr.x * nr.x + nr.y * nr.y + nr.z * nr.z + nr.w * nr.w;
        if (is_last) {
            float4 xv = *(const float4*)(x + off);
            *(float4*)(dst + off) = make_float4(xv.x - nr.x, xv.y - nr.y,
                                                xv.z - nr.z, xv.w - nr.w);
        } else {
            *(float4*)(dst + off) = nr;
        }
        if (write_hl) {
            ushort4 h, l;
            h.x = bf16rn(nr.x); l.x = bf16rn(nr.x - bf16f(h.x));
            h.y = bf16rn(nr.y); l.y = bf16rn(nr.y - bf16f(h.y));
            h.z = bf16rn(nr.z); l.z = bf16rn(nr.z - bf16f(h.z));
            h.w = bf16rn(nr.w); l.w = bf16rn(nr.w - bf16f(h.w));
            *(ushort4*)(rhi + off) = h;
            *(ushort4*)(rlo + off) = l;
        }
    }
    #pragma unroll
    for (int m = 1; m < 64; m <<= 1) lsum += __shfl_xor(lsum, m);
    if ((tid & 63) == 0)
        atomicAdd(loss_out, lsum * (1.0f / ((float)ROWS * (float)D_)));
}

// -------------------------------------------------------------------------
extern "C" void kernel_launch(void* const* d_in, const int* in_sizes, int n_in,
                              void* d_out, int out_size, void* d_ws, size_t ws_size,
                              hipStream_t stream) {
    const float* x  = (const float*)d_in[0];   // [B,N,D]
    const float* cb = (const float*)d_in[1];   // [Q,C,D]

    float* qout   = (float*)d_out;                                  // doubles as residual
    float* idx_f  = (float*)d_out + (size_t)ROWS * D_;              // [ROWS][Q_] as floats
    float* losses = idx_f + (size_t)ROWS * Q_;                      // [Q_]

    char* w = (char*)d_ws;
    unsigned short* cb_hi = (unsigned short*)w;                     // Q*C*D bf16 (8MB)
    unsigned short* cb_lo = cb_hi + (size_t)Q_ * C_ * D_;           // 8MB
    float* norms = (float*)(cb_lo + (size_t)Q_ * C_ * D_);          // Q*C
    float* st_m1 = norms + Q_ * C_;                                 // 4*ROWS
    float* st_m2 = st_m1 + 4 * ROWS;
    int*   st_i1 = (int*)(st_m2 + 4 * ROWS);
    int*   idx_i = st_i1 + 4 * ROWS;                                // ROWS
    int*   list  = idx_i + ROWS;                                    // ROWS
    int*   nflag = list + ROWS;                                     // 8 counters + pad
    unsigned short* res_hi = (unsigned short*)(nflag + 64);         // ROWS*D (32MB)
    unsigned short* res_lo = res_hi + (size_t)ROWS * D_;            // 32MB

    const size_t need = (size_t)((char*)(res_lo + (size_t)ROWS * D_) - w);
    const int preconv = (ws_size >= need) ? 1 : 0;

    hipMemsetAsync(losses, 0, Q_ * sizeof(float), stream);
    hipMemsetAsync(nflag, 0, 8 * sizeof(int), stream);   // all stages' counters
    cb_convert_kernel<<<Q_ * C_ * D_ / 1024, 256, 0, stream>>>(cb, cb_hi, cb_lo);
    code_norms_kernel<<<Q_ * C_ / 4, 256, 0, stream>>>(cb, norms);
    if (preconv)   // stage-0 A = x
        cb_convert_kernel<<<(int)((size_t)ROWS * D_ / 1024), 256, 0, stream>>>(x, res_hi, res_lo);

    for (int q = 0; q < Q_; ++q) {
        const float* src = (q == 0) ? x : qout;
        const float* cb_s = cb + (size_t)q * C_ * D_;
        if (preconv)
            rvq_gemm_pipe_kernel<<<2 * (ROWS / 128), 256, 0, stream>>>(
                res_hi, res_lo,
                cb_hi + (size_t)q * C_ * D_, cb_lo + (size_t)q * C_ * D_,
                norms + (size_t)q * C_, st_m1, st_m2, st_i1);
        else
            rvq_gemm_fallback_kernel<<<dim3(ROWS / 128, 2), 256, 0, stream>>>(
                src, cb_hi + (size_t)q * C_ * D_, cb_lo + (size_t)q * C_ * D_,
                norms + (size_t)q * C_, st_m1, st_m2, st_i1);
        merge_kernel<<<ROWS / 256, 256, 0, stream>>>(
            st_m1, st_m2, st_i1, idx_i, idx_f, list, nflag + q, q);
        rescue_kernel<<<256, 256, 0, stream>>>(
            src, cb_s, norms + (size_t)q * C_, list, nflag + q, idx_i, idx_f, q);
        update_kernel<<<ROWS / 64, 256, 0, stream>>>(
            src, qout, x, cb_s, idx_i, losses + q, res_hi, res_lo,
            (q == Q_ - 1) ? 1 : 0, (preconv && q < Q_ - 1) ? 1 : 0);
    }
}

// Round 8
// 1986.606 us; speedup vs baseline: 1.0389x; 1.0142x over previous
//
#include <hip/hip_runtime.h>
#include <math.h>

// Problem constants (ResidualVQ: B=8, N=4096, D=512, C=1024, Q=8)
#define B_   8
#define N_   4096
#define D_   512
#define C_   1024
#define Q_   8
#define ROWS (B_ * N_)   // 32768 token rows

#define TAU  0.75f       // rescue margin; 2-term approx err rms ~0.072 (10 sigma)
#define RCH  8           // rows per rescue chunk

typedef __attribute__((ext_vector_type(8))) short bf16x8;
typedef __attribute__((ext_vector_type(4))) float f32x4;

// round-to-nearest-even f32 -> bf16 (bits)
__device__ __forceinline__ unsigned short bf16rn(float f) {
    unsigned int u = __builtin_bit_cast(unsigned int, f);
    return (unsigned short)((u + 0x7fffu + ((u >> 16) & 1u)) >> 16);
}
__device__ __forceinline__ float bf16f(unsigned short h) {
    unsigned int u = ((unsigned int)h) << 16;
    return __builtin_bit_cast(float, u);
}
// LDS byte offset for tile [row][32 bf16], XOR-swizzled (<=2-way conflicts)
__device__ __forceinline__ int swzoff(int row, int q) {
    return row * 64 + ((q ^ ((row >> 1) & 3)) << 4);
}
// async global->LDS, 16B per lane. LDS dest wave-uniform+lane*16; global src per-lane.
__device__ __forceinline__ void gload16(const void* g, void* l) {
    __builtin_amdgcn_global_load_lds(
        (const __attribute__((address_space(1))) void*)g,
        (__attribute__((address_space(3))) void*)l, 16, 0, 0);
}

// -------------------------------------------------------------------------
// f32 -> hi/lo bf16 (codebooks once per call; x at stage 0)
__global__ __launch_bounds__(256)
void cb_convert_kernel(const float* __restrict__ cb,
                       unsigned short* __restrict__ hi,
                       unsigned short* __restrict__ lo) {
    const int i4 = blockIdx.x * 256 + threadIdx.x;      // float4 index
    float4 v = ((const float4*)cb)[i4];
    ushort4 h, l;
    h.x = bf16rn(v.x); l.x = bf16rn(v.x - bf16f(h.x));
    h.y = bf16rn(v.y); l.y = bf16rn(v.y - bf16f(h.y));
    h.z = bf16rn(v.z); l.z = bf16rn(v.z - bf16f(h.z));
    h.w = bf16rn(v.w); l.w = bf16rn(v.w - bf16f(h.w));
    ((ushort4*)hi)[i4] = h;
    ((ushort4*)lo)[i4] = l;
}

// ||e||^2 for every code of every stage (exact f32)
__global__ __launch_bounds__(256)
void code_norms_kernel(const float* __restrict__ cb, float* __restrict__ norms) {
    const int code = blockIdx.x * 4 + (threadIdx.x >> 6);
    const int lane = threadIdx.x & 63;
    const float* p = cb + (size_t)code * D_;
    float s = 0.f;
    #pragma unroll
    for (int d = lane * 4; d < D_; d += 256) {
        float4 v = *(const float4*)(p + d);
        s += v.x * v.x + v.y * v.y + v.z * v.z + v.w * v.w;
    }
    #pragma unroll
    for (int m = 1; m < 64; m <<= 1) s += __shfl_xor(s, m);
    if (lane == 0) norms[code] = s;
}

// -------------------------------------------------------------------------
// Pipelined 2-term split-bf16 MFMA scoring GEMM (round-6 dbuf schedule):
// score = -2 * r_hi . (e_hi + e_lo) + ||e||^2  -> 32 MFMA / wave / K-step.
// LDS tile = 3 buffers (Ahi, Bhi, Blo) x 8KB = 24KB, double-buffered (48KB).
// 24 gload16-issues per tile, 6 per wave. Per step: STAGE(next) -> ds_read
// -> MFMA -> one __syncthreads (vmcnt+lgkm drain after compute).
__global__ __launch_bounds__(256, 2)
void rvq_gemm_pipe_kernel(const unsigned short* __restrict__ ahi, // residual hi [ROWS][D_]
                          const unsigned short* __restrict__ cbh, // stage cb hi [C_][D_]
                          const unsigned short* __restrict__ cbl, // stage cb lo
                          const float* __restrict__ norms_s,      // [C_]
                          float* __restrict__ st_m1,              // [4][ROWS]
                          float* __restrict__ st_m2,              // [4][ROWS]
                          int* __restrict__ st_i1)                // [4][ROWS]
{
    __shared__ char lds[49152];        // [db:2][buf:3(Ahi,Bhi,Blo)][8192]

    const int tid  = threadIdx.x;
    const int lane = tid & 63;
    const int lc   = lane & 15;        // code/row lane within frag
    const int lq   = lane >> 4;        // k-chunk of fragment
    const int wv   = tid >> 6;
    const int wr   = wv >> 1;          // wave row-half (0..1)
    const int wc   = wv & 1;           // wave code-half (0..1)
    const int rowBase = blockIdx.x * 128;
    const int half = blockIdx.y;

    // ---- staging: 24 slots (buf b = s>>3, sub j = s&7), wave wv owns s=wv*6..+5
    const int srow = lane >> 2;                      // 0..15 (row within 1KB issue)
    const int qsw  = (lane & 3) ^ ((srow >> 1) & 3); // inverse-swizzled k-slot

    const unsigned short* bsrc[6];
    int brow[6], isB[6], lof[6];
    #pragma unroll
    for (int i = 0; i < 6; ++i) {
        const int s = wv * 6 + i;
        const int b = s >> 3;
        const int j = s & 7;
        bsrc[i] = (b == 0) ? ahi : (b == 1) ? cbh : cbl;
        brow[i] = j * 16 + srow;
        isB[i]  = (b > 0);
        lof[i]  = b * 8192 + j * 1024;
    }

    auto STAGE = [&](int db, int c, int kt) {
        char* lb = lds + db * 24576;
        #pragma unroll
        for (int i = 0; i < 6; ++i) {
            const int grow = (isB[i] ? (half * 512 + c * 128) : rowBase) + brow[i];
            gload16(bsrc[i] + (size_t)grow * D_ + kt * 32 + qsw * 8, lb + lof[i]);
        }
    };

    float c_m1 = INFINITY, c_m2 = INFINITY;
    int   c_i1 = 0;

    STAGE(0, 0, 0);
    __syncthreads();   // tile 0 landed

    for (int chunk = 0; chunk < 4; ++chunk) {
        const int codeBase = half * 512 + chunk * 128;
        f32x4 acc[4][4];
        #pragma unroll
        for (int m = 0; m < 4; ++m)
            #pragma unroll
            for (int n = 0; n < 4; ++n) acc[m][n] = (f32x4){0.f, 0.f, 0.f, 0.f};

        for (int kt = 0; kt < 16; ++kt) {
            const int t  = chunk * 16 + kt;
            const int db = t & 1;
            // prefetch next step into the other buffer (issue BEFORE compute)
            if (t + 1 < 64)
                STAGE(db ^ 1, (t + 1) >> 4, (t + 1) & 15);

            char* base = lds + db * 24576;
            char* AhiB = base;
            char* BhiB = base + 8192;
            char* BloB = base + 16384;

            bf16x8 ah[4], bh[4], bl[4];
            #pragma unroll
            for (int m = 0; m < 4; ++m) {
                const int r = wr * 64 + m * 16 + lc;
                ah[m] = *(const bf16x8*)(AhiB + swzoff(r, lq));
            }
            #pragma unroll
            for (int n = 0; n < 4; ++n) {
                const int c = wc * 64 + n * 16 + lc;
                bh[n] = *(const bf16x8*)(BhiB + swzoff(c, lq));
                bl[n] = *(const bf16x8*)(BloB + swzoff(c, lq));
            }
            #pragma unroll
            for (int m = 0; m < 4; ++m)
                #pragma unroll
                for (int n = 0; n < 4; ++n) {
                    acc[m][n] = __builtin_amdgcn_mfma_f32_16x16x32_bf16(ah[m], bh[n], acc[m][n], 0, 0, 0);
                    acc[m][n] = __builtin_amdgcn_mfma_f32_16x16x32_bf16(ah[m], bl[n], acc[m][n], 0, 0, 0);
                }
            // ONE barrier per step: ds_reads of buf[db] done (lgkmcnt), prefetch
            // for buf[db^1] committed (vmcnt) -> safe to swap.
            __syncthreads();
        }

        // ---- fold chunk scores into carried top-2 (regs + shfl only)
        const int cbase = codeBase + wc * 64;
        const float nrm0 = norms_s[cbase + lc];
        const float nrm1 = norms_s[cbase + 16 + lc];
        const float nrm2 = norms_s[cbase + 32 + lc];
        const float nrm3 = norms_s[cbase + 48 + lc];
        #pragma unroll
        for (int m = 0; m < 4; ++m) {
            #pragma unroll
            for (int r = 0; r < 4; ++r) {
                float s0 = fmaf(-2.f, acc[m][0][r], nrm0);
                float s1 = fmaf(-2.f, acc[m][1][r], nrm1);
                float s2 = fmaf(-2.f, acc[m][2][r], nrm2);
                float s3 = fmaf(-2.f, acc[m][3][r], nrm3);
                float m1 = s0, m2 = INFINITY;
                int   i1 = cbase + lc;
                if (s1 < m1) { m2 = m1; m1 = s1; i1 = cbase + 16 + lc; } else m2 = fminf(m2, s1);
                if (s2 < m1) { m2 = m1; m1 = s2; i1 = cbase + 32 + lc; } else m2 = fminf(m2, s2);
                if (s3 < m1) { m2 = m1; m1 = s3; i1 = cbase + 48 + lc; } else m2 = fminf(m2, s3);
                #pragma unroll
                for (int d = 1; d < 16; d <<= 1) {
                    float om1 = __shfl_xor(m1, d);
                    int   oi1 = __shfl_xor(i1, d);
                    float om2 = __shfl_xor(m2, d);
                    bool take = (om1 < m1) || (om1 == m1 && oi1 < i1);
                    float lose1 = take ? m1 : om1;
                    m2 = fminf(fminf(m2, om2), lose1);
                    m1 = take ? om1 : m1;
                    i1 = take ? oi1 : i1;
                }
                if (lc == (m * 4 + r)) {
                    bool take = (m1 < c_m1) || (m1 == c_m1 && i1 < c_i1);
                    float lose1 = take ? c_m1 : m1;
                    c_m2 = fminf(fminf(c_m2, m2), lose1);
                    c_m1 = take ? m1 : c_m1;
                    c_i1 = take ? i1 : c_i1;
                }
            }
        }
    }

    const int myrow = rowBase + wr * 64 + (lc >> 2) * 16 + lq * 4 + (lc & 3);
    const int quarter = half * 2 + wc;
    st_m1[quarter * ROWS + myrow] = c_m1;
    st_m2[quarter * ROWS + myrow] = c_m2;
    st_i1[quarter * ROWS + myrow] = c_i1;
}

// -------------------------------------------------------------------------
// Fallback GEMM (3-term reg-staged, in-loop A conversion) — used only if
// ws_size is too small for preconverted residuals. Proven correct (rounds 4/5).
__global__ __launch_bounds__(256, 2)
void rvq_gemm_fallback_kernel(const float* __restrict__ src,
                              const unsigned short* __restrict__ cbh,
                              const unsigned short* __restrict__ cbl,
                              const float* __restrict__ norms_s,
                              float* __restrict__ st_m1,
                              float* __restrict__ st_m2,
                              int* __restrict__ st_i1)
{
    __shared__ char lds[32768];
    char* AhiB = lds;
    char* AloB = lds + 8192;
    char* BhiB = lds + 16384;
    char* BloB = lds + 24576;

    const int tid  = threadIdx.x;
    const int lane = tid & 63;
    const int lc   = lane & 15;
    const int lq   = lane >> 4;
    const int wv   = tid >> 6;
    const int wr   = wv >> 1;
    const int wc   = wv & 1;
    const int rowBase = blockIdx.x * 128;
    const int half = blockIdx.y;

    float c_m1 = INFINITY, c_m2 = INFINITY;
    int   c_i1 = 0;

    const int arow  = tid >> 1;
    const int ahalf = tid & 1;

    for (int chunk = 0; chunk < 4; ++chunk) {
        const int codeBase = half * 512 + chunk * 128;
        f32x4 acc[4][4];
        #pragma unroll
        for (int m = 0; m < 4; ++m)
            #pragma unroll
            for (int n = 0; n < 4; ++n) acc[m][n] = (f32x4){0.f, 0.f, 0.f, 0.f};

        for (int kt = 0; kt < D_ / 32; ++kt) {
            __syncthreads();
            {
                const float* ap = src + (size_t)(rowBase + arow) * D_ + kt * 32 + ahalf * 16;
                float fv[16];
                *(float4*)&fv[0]  = ((const float4*)ap)[0];
                *(float4*)&fv[4]  = ((const float4*)ap)[1];
                *(float4*)&fv[8]  = ((const float4*)ap)[2];
                *(float4*)&fv[12] = ((const float4*)ap)[3];
                bf16x8 H0, H1, L0, L1;
                #pragma unroll
                for (int j = 0; j < 8; ++j) {
                    unsigned short h0 = bf16rn(fv[j]);
                    H0[j] = (short)h0;
                    L0[j] = (short)bf16rn(fv[j] - bf16f(h0));
                    unsigned short h1 = bf16rn(fv[j + 8]);
                    H1[j] = (short)h1;
                    L1[j] = (short)bf16rn(fv[j + 8] - bf16f(h1));
                }
                const int q0 = ahalf * 2;
                *(bf16x8*)(AhiB + swzoff(arow, q0))     = H0;
                *(bf16x8*)(AhiB + swzoff(arow, q0 + 1)) = H1;
                *(bf16x8*)(AloB + swzoff(arow, q0))     = L0;
                *(bf16x8*)(AloB + swzoff(arow, q0 + 1)) = L1;
            }
            {
                const size_t boff = (size_t)(codeBase + arow) * D_ + kt * 32 + ahalf * 16;
                bf16x8 bh0 = *(const bf16x8*)(cbh + boff);
                bf16x8 bh1 = *(const bf16x8*)(cbh + boff + 8);
                bf16x8 bl0 = *(const bf16x8*)(cbl + boff);
                bf16x8 bl1 = *(const bf16x8*)(cbl + boff + 8);
                const int q0 = ahalf * 2;
                *(bf16x8*)(BhiB + swzoff(arow, q0))     = bh0;
                *(bf16x8*)(BhiB + swzoff(arow, q0 + 1)) = bh1;
                *(bf16x8*)(BloB + swzoff(arow, q0))     = bl0;
                *(bf16x8*)(BloB + swzoff(arow, q0 + 1)) = bl1;
            }
            __syncthreads();
            bf16x8 ah[4], al[4], bh[4], bl[4];
            #pragma unroll
            for (int m = 0; m < 4; ++m) {
                const int r = wr * 64 + m * 16 + lc;
                ah[m] = *(const bf16x8*)(AhiB + swzoff(r, lq));
                al[m] = *(const bf16x8*)(AloB + swzoff(r, lq));
            }
            #pragma unroll
            for (int n = 0; n < 4; ++n) {
                const int c = wc * 64 + n * 16 + lc;
                bh[n] = *(const bf16x8*)(BhiB + swzoff(c, lq));
                bl[n] = *(const bf16x8*)(BloB + swzoff(c, lq));
            }
            #pragma unroll
            for (int m = 0; m < 4; ++m)
                #pragma unroll
                for (int n = 0; n < 4; ++n) {
                    acc[m][n] = __builtin_amdgcn_mfma_f32_16x16x32_bf16(ah[m], bh[n], acc[m][n], 0, 0, 0);
                    acc[m][n] = __builtin_amdgcn_mfma_f32_16x16x32_bf16(ah[m], bl[n], acc[m][n], 0, 0, 0);
                    acc[m][n] = __builtin_amdgcn_mfma_f32_16x16x32_bf16(al[m], bh[n], acc[m][n], 0, 0, 0);
                }
        }

        const int cbase = codeBase + wc * 64;
        const float nrm0 = norms_s[cbase + lc];
        const float nrm1 = norms_s[cbase + 16 + lc];
        const float nrm2 = norms_s[cbase + 32 + lc];
        const float nrm3 = norms_s[cbase + 48 + lc];
        #pragma unroll
        for (int m = 0; m < 4; ++m) {
            #pragma unroll
            for (int r = 0; r < 4; ++r) {
                float s0 = fmaf(-2.f, acc[m][0][r], nrm0);
                float s1 = fmaf(-2.f, acc[m][1][r], nrm1);
                float s2 = fmaf(-2.f, acc[m][2][r], nrm2);
                float s3 = fmaf(-2.f, acc[m][3][r], nrm3);
                float m1 = s0, m2 = INFINITY;
                int   i1 = cbase + lc;
                if (s1 < m1) { m2 = m1; m1 = s1; i1 = cbase + 16 + lc; } else m2 = fminf(m2, s1);
                if (s2 < m1) { m2 = m1; m1 = s2; i1 = cbase + 32 + lc; } else m2 = fminf(m2, s2);
                if (s3 < m1) { m2 = m1; m1 = s3; i1 = cbase + 48 + lc; } else m2 = fminf(m2, s3);
                #pragma unroll
                for (int d = 1; d < 16; d <<= 1) {
                    float om1 = __shfl_xor(m1, d);
                    int   oi1 = __shfl_xor(i1, d);
                    float om2 = __shfl_xor(m2, d);
                    bool take = (om1 < m1) || (om1 == m1 && oi1 < i1);
                    float lose1 = take ? m1 : om1;
                    m2 = fminf(fminf(m2, om2), lose1);
                    m1 = take ? om1 : m1;
                    i1 = take ? oi1 : i1;
                }
                if (lc == (m * 4 + r)) {
                    bool take = (m1 < c_m1) || (m1 == c_m1 && i1 < c_i1);
                    float lose1 = take ? c_m1 : m1;
                    c_m2 = fminf(fminf(c_m2, m2), lose1);
                    c_m1 = take ? m1 : c_m1;
                    c_i1 = take ? i1 : c_i1;
                }
            }
        }
    }

    const int myrow = rowBase + wr * 64 + (lc >> 2) * 16 + lq * 4 + (lc & 3);
    const int quarter = half * 2 + wc;
    st_m1[quarter * ROWS + myrow] = c_m1;
    st_m2[quarter * ROWS + myrow] = c_m2;
    st_i1[quarter * ROWS + myrow] = c_i1;
}

// -------------------------------------------------------------------------
// merge 4 quarters -> final idx; near-tie rows appended to compact rescue list
__global__ __launch_bounds__(256)
void merge_kernel(const float* __restrict__ st_m1, const float* __restrict__ st_m2,
                  const int* __restrict__ st_i1,
                  int* __restrict__ idx_i, float* __restrict__ idx_f,
                  int* __restrict__ list, int* __restrict__ nflag, int q) {
    const int row = blockIdx.x * 256 + threadIdx.x;
    float m1 = st_m1[row], m2 = st_m2[row];
    int   i1 = st_i1[row];
    #pragma unroll
    for (int qt = 1; qt < 4; ++qt) {
        float om1 = st_m1[qt * ROWS + row];
        float om2 = st_m2[qt * ROWS + row];
        int   oi1 = st_i1[qt * ROWS + row];
        if (om1 < m1) { m2 = fminf(m1, om2); m1 = om1; i1 = oi1; }
        else          { m2 = fminf(m2, om1); }
    }
    idx_i[row] = i1;
    idx_f[(size_t)row * Q_ + q] = (float)i1;
    if (m2 - m1 < TAU) {
        const int p = atomicAdd(nflag, 1);
        list[p] = row;
    }
}

// -------------------------------------------------------------------------
// Exact-f32 re-argmin for near-tie rows, compact-list driven.
__global__ __launch_bounds__(256)
void rescue_kernel(const float* __restrict__ src, const float* __restrict__ cb,
                   const float* __restrict__ norms_s,
                   const int* __restrict__ list, const int* __restrict__ nflag_p,
                   int* __restrict__ idx_i, float* __restrict__ idx_f, int q)
{
    __shared__ float As[D_][RCH];      // residual rows, [k][row] (16 KB)
    __shared__ int   rows_s[RCH];
    __shared__ float wm[4][RCH];
    __shared__ int   wi[4][RCH];
    const int nflag = nflag_p[0];
    const int tid = threadIdx.x;

    for (int chunk = blockIdx.x; chunk * RCH < nflag; chunk += gridDim.x) {
        __syncthreads();
        if (tid < RCH) {
            const int li = chunk * RCH + tid;
            rows_s[tid] = list[li < nflag ? li : nflag - 1];   // pad = dup last
        }
        __syncthreads();
        #pragma unroll
        for (int i = 0; i < 4; ++i) {
            const int v  = tid + 256 * i;
            const int r  = v >> 7;
            const int k4 = (v & 127) * 4;
            float4 f = *(const float4*)(src + (size_t)rows_s[r] * D_ + k4);
            As[k4 + 0][r] = f.x; As[k4 + 1][r] = f.y;
            As[k4 + 2][r] = f.z; As[k4 + 3][r] = f.w;
        }
        __syncthreads();

        float acc[4][RCH];
        #pragma unroll
        for (int j = 0; j < 4; ++j)
            #pragma unroll
            for (int r = 0; r < RCH; ++r) acc[j][r] = 0.f;

        for (int k = 0; k < D_; k += 4) {
            float4 bq[4];
            #pragma unroll
            for (int j = 0; j < 4; ++j)
                bq[j] = *(const float4*)(cb + (size_t)(tid + 256 * j) * D_ + k);
            const float* bp = (const float*)&bq[0];
            const float* ap = &As[k][0];
            #pragma unroll
            for (int e = 0; e < 4; ++e)
                #pragma unroll
                for (int r = 0; r < RCH; ++r) {
                    const float a = ap[e * RCH + r];
                    #pragma unroll
                    for (int j = 0; j < 4; ++j)
                        acc[j][r] = fmaf(bp[j * 4 + e], a, acc[j][r]);
                }
        }

        float m1[RCH]; int i1[RCH];
        #pragma unroll
        for (int r = 0; r < RCH; ++r) { m1[r] = INFINITY; i1[r] = 0; }
        #pragma unroll
        for (int j = 0; j < 4; ++j) {
            const int c = tid + 256 * j;
            const float nr = norms_s[c];
            #pragma unroll
            for (int r = 0; r < RCH; ++r) {
                const float s = fmaf(-2.f, acc[j][r], nr);
                if (s < m1[r]) { m1[r] = s; i1[r] = c; }
            }
        }
        #pragma unroll
        for (int d = 1; d < 64; d <<= 1)
            #pragma unroll
            for (int r = 0; r < RCH; ++r) {
                const float om = __shfl_xor(m1[r], d);
                const int   oi = __shfl_xor(i1[r], d);
                if (om < m1[r] || (om == m1[r] && oi < i1[r])) { m1[r] = om; i1[r] = oi; }
            }
        if ((tid & 63) == 0)
            #pragma unroll
            for (int r = 0; r < RCH; ++r) { wm[tid >> 6][r] = m1[r]; wi[tid >> 6][r] = i1[r]; }
        __syncthreads();
        if (tid < RCH) {
            float bm = wm[0][tid]; int bi = wi[0][tid];
            #pragma unroll
            for (int w = 1; w < 4; ++w)
                if (wm[w][tid] < bm || (wm[w][tid] == bm && wi[w][tid] < bi)) {
                    bm = wm[w][tid]; bi = wi[w][tid];
                }
            const int li = chunk * RCH + tid;
            if (li < nflag) {
                const int row = rows_s[tid];
                idx_i[row] = bi;
                idx_f[(size_t)row * Q_ + q] = (float)bi;
            }
        }
    }
}

// -------------------------------------------------------------------------
// residual update: newres = res - cb[idx] (exact f32); loss; final qout.
// write_hl: also emit bf16 HI of newres for next stage's GEMM A (lo not needed).
__global__ __launch_bounds__(256)
void update_kernel(const float* __restrict__ src, float* __restrict__ dst,
                   const float* __restrict__ x, const float* __restrict__ cb,
                   const int* __restrict__ idx_i, float* __restrict__ loss_out,
                   unsigned short* __restrict__ rhi,
                   int is_last, int write_hl) {
    __shared__ int ids[64];
    const int tid = threadIdx.x;
    const int rowBase = blockIdx.x * 64;
    if (tid < 64) ids[tid] = idx_i[rowBase + tid];
    __syncthreads();
    float lsum = 0.f;
    #pragma unroll 4
    for (int e4 = tid; e4 < 64 * D_ / 4; e4 += 256) {
        const int row  = e4 >> 7;
        const int d    = (e4 & 127) * 4;
        const int code = ids[row];
        const size_t off = (size_t)(rowBase + row) * D_ + d;
        float4 r = *(const float4*)(src + off);
        float4 e = *(const float4*)(cb + (size_t)code * D_ + d);
        float4 nr = make_float4(r.x - e.x, r.y - e.y, r.z - e.z, r.w - e.w);
        lsum += nr.x * nr.x + nr.y * nr.y + nr.z * nr.z + nr.w * nr.w;
        if (is_last) {
            float4 xv = *(const float4*)(x + off);
            *(float4*)(dst + off) = make_float4(xv.x - nr.x, xv.y - nr.y,
                                                xv.z - nr.z, xv.w - nr.w);
        } else {
            *(float4*)(dst + off) = nr;
        }
        if (write_hl) {
            ushort4 h;
            h.x = bf16rn(nr.x);
            h.y = bf16rn(nr.y);
            h.z = bf16rn(nr.z);
            h.w = bf16rn(nr.w);
            *(ushort4*)(rhi + off) = h;
        }
    }
    #pragma unroll
    for (int m = 1; m < 64; m <<= 1) lsum += __shfl_xor(lsum, m);
    if ((tid & 63) == 0)
        atomicAdd(loss_out, lsum * (1.0f / ((float)ROWS * (float)D_)));
}

// -------------------------------------------------------------------------
extern "C" void kernel_launch(void* const* d_in, const int* in_sizes, int n_in,
                              void* d_out, int out_size, void* d_ws, size_t ws_size,
                              hipStream_t stream) {
    const float* x  = (const float*)d_in[0];   // [B,N,D]
    const float* cb = (const float*)d_in[1];   // [Q,C,D]

    float* qout   = (float*)d_out;                                  // doubles as residual
    float* idx_f  = (float*)d_out + (size_t)ROWS * D_;              // [ROWS][Q_] as floats
    float* losses = idx_f + (size_t)ROWS * Q_;                      // [Q_]

    char* w = (char*)d_ws;
    unsigned short* cb_hi = (unsigned short*)w;                     // Q*C*D bf16 (8MB)
    unsigned short* cb_lo = cb_hi + (size_t)Q_ * C_ * D_;           // 8MB
    float* norms = (float*)(cb_lo + (size_t)Q_ * C_ * D_);          // Q*C
    float* st_m1 = norms + Q_ * C_;                                 // 4*ROWS
    float* st_m2 = st_m1 + 4 * ROWS;
    int*   st_i1 = (int*)(st_m2 + 4 * ROWS);
    int*   idx_i = st_i1 + 4 * ROWS;                                // ROWS
    int*   list  = idx_i + ROWS;                                    // ROWS
    int*   nflag = list + ROWS;                                     // 8 counters + pad
    unsigned short* res_hi = (unsigned short*)(nflag + 64);         // ROWS*D (32MB)
    unsigned short* res_lo = res_hi + (size_t)ROWS * D_;            // 32MB (stage-0 scratch)

    const size_t need = (size_t)((char*)(res_lo + (size_t)ROWS * D_) - w);
    const int preconv = (ws_size >= need) ? 1 : 0;

    hipMemsetAsync(losses, 0, Q_ * sizeof(float), stream);
    hipMemsetAsync(nflag, 0, 8 * sizeof(int), stream);   // all stages' counters
    cb_convert_kernel<<<Q_ * C_ * D_ / 1024, 256, 0, stream>>>(cb, cb_hi, cb_lo);
    code_norms_kernel<<<Q_ * C_ / 4, 256, 0, stream>>>(cb, norms);
    if (preconv)   // stage-0 A = x (lo written to scratch, unused)
        cb_convert_kernel<<<(int)((size_t)ROWS * D_ / 1024), 256, 0, stream>>>(x, res_hi, res_lo);

    for (int q = 0; q < Q_; ++q) {
        const float* src = (q == 0) ? x : qout;
        const float* cb_s = cb + (size_t)q * C_ * D_;
        if (preconv)
            rvq_gemm_pipe_kernel<<<dim3(ROWS / 128, 2), 256, 0, stream>>>(
                res_hi,
                cb_hi + (size_t)q * C_ * D_, cb_lo + (size_t)q * C_ * D_,
                norms + (size_t)q * C_, st_m1, st_m2, st_i1);
        else
            rvq_gemm_fallback_kernel<<<dim3(ROWS / 128, 2), 256, 0, stream>>>(
                src, cb_hi + (size_t)q * C_ * D_, cb_lo + (size_t)q * C_ * D_,
                norms + (size_t)q * C_, st_m1, st_m2, st_i1);
        merge_kernel<<<ROWS / 256, 256, 0, stream>>>(
            st_m1, st_m2, st_i1, idx_i, idx_f, list, nflag + q, q);
        rescue_kernel<<<256, 256, 0, stream>>>(
            src, cb_s, norms + (size_t)q * C_, list, nflag + q, idx_i, idx_f, q);
        update_kernel<<<ROWS / 64, 256, 0, stream>>>(
            src, qout, x, cb_s, idx_i, losses + q, res_hi,
            (q == Q_ - 1) ? 1 : 0, (preconv && q < Q_ - 1) ? 1 : 0);
    }
}

// Round 9
// 1835.213 us; speedup vs baseline: 1.1246x; 1.0825x over previous
//
#include <hip/hip_runtime.h>
#include <math.h>

// Problem constants (ResidualVQ: B=8, N=4096, D=512, C=1024, Q=8)
#define B_   8
#define N_   4096
#define D_   512
#define C_   1024
#define Q_   8
#define ROWS (B_ * N_)   // 32768 token rows

#define TAU  0.75f       // rescue margin; 2-term approx err rms ~0.072 (10 sigma)
#define RCH  8           // rows per rescue chunk

typedef __attribute__((ext_vector_type(8))) short bf16x8;
typedef __attribute__((ext_vector_type(4))) float f32x4;

// round-to-nearest-even f32 -> bf16 (bits)
__device__ __forceinline__ unsigned short bf16rn(float f) {
    unsigned int u = __builtin_bit_cast(unsigned int, f);
    return (unsigned short)((u + 0x7fffu + ((u >> 16) & 1u)) >> 16);
}
__device__ __forceinline__ float bf16f(unsigned short h) {
    unsigned int u = ((unsigned int)h) << 16;
    return __builtin_bit_cast(float, u);
}
// LDS byte offset for tile [row][32 bf16], XOR-swizzled (<=2-way conflicts)
__device__ __forceinline__ int swzoff(int row, int q) {
    return row * 64 + ((q ^ ((row >> 1) & 3)) << 4);
}
// async global->LDS, 16B per lane. LDS dest wave-uniform+lane*16; global src per-lane.
__device__ __forceinline__ void gload16(const void* g, void* l) {
    __builtin_amdgcn_global_load_lds(
        (const __attribute__((address_space(1))) void*)g,
        (__attribute__((address_space(3))) void*)l, 16, 0, 0);
}

// -------------------------------------------------------------------------
// f32 -> hi/lo bf16 (codebooks once per call; x at stage 0)
__global__ __launch_bounds__(256)
void cb_convert_kernel(const float* __restrict__ cb,
                       unsigned short* __restrict__ hi,
                       unsigned short* __restrict__ lo) {
    const int i4 = blockIdx.x * 256 + threadIdx.x;      // float4 index
    float4 v = ((const float4*)cb)[i4];
    ushort4 h, l;
    h.x = bf16rn(v.x); l.x = bf16rn(v.x - bf16f(h.x));
    h.y = bf16rn(v.y); l.y = bf16rn(v.y - bf16f(h.y));
    h.z = bf16rn(v.z); l.z = bf16rn(v.z - bf16f(h.z));
    h.w = bf16rn(v.w); l.w = bf16rn(v.w - bf16f(h.w));
    ((ushort4*)hi)[i4] = h;
    ((ushort4*)lo)[i4] = l;
}

// ||e||^2 for every code of every stage (exact f32)
__global__ __launch_bounds__(256)
void code_norms_kernel(const float* __restrict__ cb, float* __restrict__ norms) {
    const int code = blockIdx.x * 4 + (threadIdx.x >> 6);
    const int lane = threadIdx.x & 63;
    const float* p = cb + (size_t)code * D_;
    float s = 0.f;
    #pragma unroll
    for (int d = lane * 4; d < D_; d += 256) {
        float4 v = *(const float4*)(p + d);
        s += v.x * v.x + v.y * v.y + v.z * v.z + v.w * v.w;
    }
    #pragma unroll
    for (int m = 1; m < 64; m <<= 1) s += __shfl_xor(s, m);
    if (lane == 0) norms[code] = s;
}

// -------------------------------------------------------------------------
// Pipelined 2-term split-bf16 MFMA scoring GEMM (round-6 dbuf schedule):
// score = -2 * r_hi . (e_hi + e_lo) + ||e||^2  -> 32 MFMA / wave / K-step.
__global__ __launch_bounds__(256, 2)
void rvq_gemm_pipe_kernel(const unsigned short* __restrict__ ahi, // residual hi [ROWS][D_]
                          const unsigned short* __restrict__ cbh, // stage cb hi [C_][D_]
                          const unsigned short* __restrict__ cbl, // stage cb lo
                          const float* __restrict__ norms_s,      // [C_]
                          float* __restrict__ st_m1,              // [4][ROWS]
                          float* __restrict__ st_m2,              // [4][ROWS]
                          int* __restrict__ st_i1)                // [4][ROWS]
{
    __shared__ char lds[49152];        // [db:2][buf:3(Ahi,Bhi,Blo)][8192]

    const int tid  = threadIdx.x;
    const int lane = tid & 63;
    const int lc   = lane & 15;        // code/row lane within frag
    const int lq   = lane >> 4;        // k-chunk of fragment
    const int wv   = tid >> 6;
    const int wr   = wv >> 1;          // wave row-half (0..1)
    const int wc   = wv & 1;           // wave code-half (0..1)
    const int rowBase = blockIdx.x * 128;
    const int half = blockIdx.y;

    // ---- staging: 24 slots (buf b = s>>3, sub j = s&7), wave wv owns s=wv*6..+5
    const int srow = lane >> 2;                      // 0..15 (row within 1KB issue)
    const int qsw  = (lane & 3) ^ ((srow >> 1) & 3); // inverse-swizzled k-slot

    const unsigned short* bsrc[6];
    int brow[6], isB[6], lof[6];
    #pragma unroll
    for (int i = 0; i < 6; ++i) {
        const int s = wv * 6 + i;
        const int b = s >> 3;
        const int j = s & 7;
        bsrc[i] = (b == 0) ? ahi : (b == 1) ? cbh : cbl;
        brow[i] = j * 16 + srow;
        isB[i]  = (b > 0);
        lof[i]  = b * 8192 + j * 1024;
    }

    auto STAGE = [&](int db, int c, int kt) {
        char* lb = lds + db * 24576;
        #pragma unroll
        for (int i = 0; i < 6; ++i) {
            const int grow = (isB[i] ? (half * 512 + c * 128) : rowBase) + brow[i];
            gload16(bsrc[i] + (size_t)grow * D_ + kt * 32 + qsw * 8, lb + lof[i]);
        }
    };

    float c_m1 = INFINITY, c_m2 = INFINITY;
    int   c_i1 = 0;

    STAGE(0, 0, 0);
    __syncthreads();   // tile 0 landed

    for (int chunk = 0; chunk < 4; ++chunk) {
        const int codeBase = half * 512 + chunk * 128;
        f32x4 acc[4][4];
        #pragma unroll
        for (int m = 0; m < 4; ++m)
            #pragma unroll
            for (int n = 0; n < 4; ++n) acc[m][n] = (f32x4){0.f, 0.f, 0.f, 0.f};

        for (int kt = 0; kt < 16; ++kt) {
            const int t  = chunk * 16 + kt;
            const int db = t & 1;
            // prefetch next step into the other buffer (issue BEFORE compute)
            if (t + 1 < 64)
                STAGE(db ^ 1, (t + 1) >> 4, (t + 1) & 15);

            char* base = lds + db * 24576;
            char* AhiB = base;
            char* BhiB = base + 8192;
            char* BloB = base + 16384;

            bf16x8 ah[4], bh[4], bl[4];
            #pragma unroll
            for (int m = 0; m < 4; ++m) {
                const int r = wr * 64 + m * 16 + lc;
                ah[m] = *(const bf16x8*)(AhiB + swzoff(r, lq));
            }
            #pragma unroll
            for (int n = 0; n < 4; ++n) {
                const int c = wc * 64 + n * 16 + lc;
                bh[n] = *(const bf16x8*)(BhiB + swzoff(c, lq));
                bl[n] = *(const bf16x8*)(BloB + swzoff(c, lq));
            }
            #pragma unroll
            for (int m = 0; m < 4; ++m)
                #pragma unroll
                for (int n = 0; n < 4; ++n) {
                    acc[m][n] = __builtin_amdgcn_mfma_f32_16x16x32_bf16(ah[m], bh[n], acc[m][n], 0, 0, 0);
                    acc[m][n] = __builtin_amdgcn_mfma_f32_16x16x32_bf16(ah[m], bl[n], acc[m][n], 0, 0, 0);
                }
            // ONE barrier per step: ds_reads of buf[db] done (lgkmcnt), prefetch
            // for buf[db^1] committed (vmcnt) -> safe to swap.
            __syncthreads();
        }

        // ---- fold chunk scores into carried top-2 (regs + shfl only)
        const int cbase = codeBase + wc * 64;
        const float nrm0 = norms_s[cbase + lc];
        const float nrm1 = norms_s[cbase + 16 + lc];
        const float nrm2 = norms_s[cbase + 32 + lc];
        const float nrm3 = norms_s[cbase + 48 + lc];
        #pragma unroll
        for (int m = 0; m < 4; ++m) {
            #pragma unroll
            for (int r = 0; r < 4; ++r) {
                float s0 = fmaf(-2.f, acc[m][0][r], nrm0);
                float s1 = fmaf(-2.f, acc[m][1][r], nrm1);
                float s2 = fmaf(-2.f, acc[m][2][r], nrm2);
                float s3 = fmaf(-2.f, acc[m][3][r], nrm3);
                float m1 = s0, m2 = INFINITY;
                int   i1 = cbase + lc;
                if (s1 < m1) { m2 = m1; m1 = s1; i1 = cbase + 16 + lc; } else m2 = fminf(m2, s1);
                if (s2 < m1) { m2 = m1; m1 = s2; i1 = cbase + 32 + lc; } else m2 = fminf(m2, s2);
                if (s3 < m1) { m2 = m1; m1 = s3; i1 = cbase + 48 + lc; } else m2 = fminf(m2, s3);
                #pragma unroll
                for (int d = 1; d < 16; d <<= 1) {
                    float om1 = __shfl_xor(m1, d);
                    int   oi1 = __shfl_xor(i1, d);
                    float om2 = __shfl_xor(m2, d);
                    bool take = (om1 < m1) || (om1 == m1 && oi1 < i1);
                    float lose1 = take ? m1 : om1;
                    m2 = fminf(fminf(m2, om2), lose1);
                    m1 = take ? om1 : m1;
                    i1 = take ? oi1 : i1;
                }
                if (lc == (m * 4 + r)) {
                    bool take = (m1 < c_m1) || (m1 == c_m1 && i1 < c_i1);
                    float lose1 = take ? c_m1 : m1;
                    c_m2 = fminf(fminf(c_m2, m2), lose1);
                    c_m1 = take ? m1 : c_m1;
                    c_i1 = take ? i1 : c_i1;
                }
            }
        }
    }

    const int myrow = rowBase + wr * 64 + (lc >> 2) * 16 + lq * 4 + (lc & 3);
    const int quarter = half * 2 + wc;
    st_m1[quarter * ROWS + myrow] = c_m1;
    st_m2[quarter * ROWS + myrow] = c_m2;
    st_i1[quarter * ROWS + myrow] = c_i1;
}

// -------------------------------------------------------------------------
// Fallback GEMM (3-term reg-staged, in-loop A conversion) — used only if
// ws_size is too small for preconverted residuals. Proven correct (rounds 4/5).
__global__ __launch_bounds__(256, 2)
void rvq_gemm_fallback_kernel(const float* __restrict__ src,
                              const unsigned short* __restrict__ cbh,
                              const unsigned short* __restrict__ cbl,
                              const float* __restrict__ norms_s,
                              float* __restrict__ st_m1,
                              float* __restrict__ st_m2,
                              int* __restrict__ st_i1)
{
    __shared__ char lds[32768];
    char* AhiB = lds;
    char* AloB = lds + 8192;
    char* BhiB = lds + 16384;
    char* BloB = lds + 24576;

    const int tid  = threadIdx.x;
    const int lane = tid & 63;
    const int lc   = lane & 15;
    const int lq   = lane >> 4;
    const int wv   = tid >> 6;
    const int wr   = wv >> 1;
    const int wc   = wv & 1;
    const int rowBase = blockIdx.x * 128;
    const int half = blockIdx.y;

    float c_m1 = INFINITY, c_m2 = INFINITY;
    int   c_i1 = 0;

    const int arow  = tid >> 1;
    const int ahalf = tid & 1;

    for (int chunk = 0; chunk < 4; ++chunk) {
        const int codeBase = half * 512 + chunk * 128;
        f32x4 acc[4][4];
        #pragma unroll
        for (int m = 0; m < 4; ++m)
            #pragma unroll
            for (int n = 0; n < 4; ++n) acc[m][n] = (f32x4){0.f, 0.f, 0.f, 0.f};

        for (int kt = 0; kt < D_ / 32; ++kt) {
            __syncthreads();
            {
                const float* ap = src + (size_t)(rowBase + arow) * D_ + kt * 32 + ahalf * 16;
                float fv[16];
                *(float4*)&fv[0]  = ((const float4*)ap)[0];
                *(float4*)&fv[4]  = ((const float4*)ap)[1];
                *(float4*)&fv[8]  = ((const float4*)ap)[2];
                *(float4*)&fv[12] = ((const float4*)ap)[3];
                bf16x8 H0, H1, L0, L1;
                #pragma unroll
                for (int j = 0; j < 8; ++j) {
                    unsigned short h0 = bf16rn(fv[j]);
                    H0[j] = (short)h0;
                    L0[j] = (short)bf16rn(fv[j] - bf16f(h0));
                    unsigned short h1 = bf16rn(fv[j + 8]);
                    H1[j] = (short)h1;
                    L1[j] = (short)bf16rn(fv[j + 8] - bf16f(h1));
                }
                const int q0 = ahalf * 2;
                *(bf16x8*)(AhiB + swzoff(arow, q0))     = H0;
                *(bf16x8*)(AhiB + swzoff(arow, q0 + 1)) = H1;
                *(bf16x8*)(AloB + swzoff(arow, q0))     = L0;
                *(bf16x8*)(AloB + swzoff(arow, q0 + 1)) = L1;
            }
            {
                const size_t boff = (size_t)(codeBase + arow) * D_ + kt * 32 + ahalf * 16;
                bf16x8 bh0 = *(const bf16x8*)(cbh + boff);
                bf16x8 bh1 = *(const bf16x8*)(cbh + boff + 8);
                bf16x8 bl0 = *(const bf16x8*)(cbl + boff);
                bf16x8 bl1 = *(const bf16x8*)(cbl + boff + 8);
                const int q0 = ahalf * 2;
                *(bf16x8*)(BhiB + swzoff(arow, q0))     = bh0;
                *(bf16x8*)(BhiB + swzoff(arow, q0 + 1)) = bh1;
                *(bf16x8*)(BloB + swzoff(arow, q0))     = bl0;
                *(bf16x8*)(BloB + swzoff(arow, q0 + 1)) = bl1;
            }
            __syncthreads();
            bf16x8 ah[4], al[4], bh[4], bl[4];
            #pragma unroll
            for (int m = 0; m < 4; ++m) {
                const int r = wr * 64 + m * 16 + lc;
                ah[m] = *(const bf16x8*)(AhiB + swzoff(r, lq));
                al[m] = *(const bf16x8*)(AloB + swzoff(r, lq));
            }
            #pragma unroll
            for (int n = 0; n < 4; ++n) {
                const int c = wc * 64 + n * 16 + lc;
                bh[n] = *(const bf16x8*)(BhiB + swzoff(c, lq));
                bl[n] = *(const bf16x8*)(BloB + swzoff(c, lq));
            }
            #pragma unroll
            for (int m = 0; m < 4; ++m)
                #pragma unroll
                for (int n = 0; n < 4; ++n) {
                    acc[m][n] = __builtin_amdgcn_mfma_f32_16x16x32_bf16(ah[m], bh[n], acc[m][n], 0, 0, 0);
                    acc[m][n] = __builtin_amdgcn_mfma_f32_16x16x32_bf16(ah[m], bl[n], acc[m][n], 0, 0, 0);
                    acc[m][n] = __builtin_amdgcn_mfma_f32_16x16x32_bf16(al[m], bh[n], acc[m][n], 0, 0, 0);
                }
        }

        const int cbase = codeBase + wc * 64;
        const float nrm0 = norms_s[cbase + lc];
        const float nrm1 = norms_s[cbase + 16 + lc];
        const float nrm2 = norms_s[cbase + 32 + lc];
        const float nrm3 = norms_s[cbase + 48 + lc];
        #pragma unroll
        for (int m = 0; m < 4; ++m) {
            #pragma unroll
            for (int r = 0; r < 4; ++r) {
                float s0 = fmaf(-2.f, acc[m][0][r], nrm0);
                float s1 = fmaf(-2.f, acc[m][1][r], nrm1);
                float s2 = fmaf(-2.f, acc[m][2][r], nrm2);
                float s3 = fmaf(-2.f, acc[m][3][r], nrm3);
                float m1 = s0, m2 = INFINITY;
                int   i1 = cbase + lc;
                if (s1 < m1) { m2 = m1; m1 = s1; i1 = cbase + 16 + lc; } else m2 = fminf(m2, s1);
                if (s2 < m1) { m2 = m1; m1 = s2; i1 = cbase + 32 + lc; } else m2 = fminf(m2, s2);
                if (s3 < m1) { m2 = m1; m1 = s3; i1 = cbase + 48 + lc; } else m2 = fminf(m2, s3);
                #pragma unroll
                for (int d = 1; d < 16; d <<= 1) {
                    float om1 = __shfl_xor(m1, d);
                    int   oi1 = __shfl_xor(i1, d);
                    float om2 = __shfl_xor(m2, d);
                    bool take = (om1 < m1) || (om1 == m1 && oi1 < i1);
                    float lose1 = take ? m1 : om1;
                    m2 = fminf(fminf(m2, om2), lose1);
                    m1 = take ? om1 : m1;
                    i1 = take ? oi1 : i1;
                }
                if (lc == (m * 4 + r)) {
                    bool take = (m1 < c_m1) || (m1 == c_m1 && i1 < c_i1);
                    float lose1 = take ? c_m1 : m1;
                    c_m2 = fminf(fminf(c_m2, m2), lose1);
                    c_m1 = take ? m1 : c_m1;
                    c_i1 = take ? i1 : c_i1;
                }
            }
        }
    }

    const int myrow = rowBase + wr * 64 + (lc >> 2) * 16 + lq * 4 + (lc & 3);
    const int quarter = half * 2 + wc;
    st_m1[quarter * ROWS + myrow] = c_m1;
    st_m2[quarter * ROWS + myrow] = c_m2;
    st_i1[quarter * ROWS + myrow] = c_i1;
}

// -------------------------------------------------------------------------
// merge 4 quarters -> final idx; near-tie rows appended to compact rescue list
__global__ __launch_bounds__(256)
void merge_kernel(const float* __restrict__ st_m1, const float* __restrict__ st_m2,
                  const int* __restrict__ st_i1,
                  int* __restrict__ idx_i, float* __restrict__ idx_f,
                  int* __restrict__ list, int* __restrict__ nflag, int q) {
    const int row = blockIdx.x * 256 + threadIdx.x;
    float m1 = st_m1[row], m2 = st_m2[row];
    int   i1 = st_i1[row];
    #pragma unroll
    for (int qt = 1; qt < 4; ++qt) {
        float om1 = st_m1[qt * ROWS + row];
        float om2 = st_m2[qt * ROWS + row];
        int   oi1 = st_i1[qt * ROWS + row];
        if (om1 < m1) { m2 = fminf(m1, om2); m1 = om1; i1 = oi1; }
        else          { m2 = fminf(m2, om1); }
    }
    idx_i[row] = i1;
    idx_f[(size_t)row * Q_ + q] = (float)i1;
    if (m2 - m1 < TAU) {
        const int p = atomicAdd(nflag, 1);
        list[p] = row;
    }
}

// -------------------------------------------------------------------------
// Exact-f32 re-argmin for near-tie rows, compact-list driven.
// Software-pipelined k-loop: two named register groups (pa*/pb*) alternate;
// 4 independent 1KB loads stay in flight under each 128-FMA half-step, so
// L2 latency (~200cy) hides under VALU (~256cy). (Round-8 version serialized
// load-wait per iteration: VALUBusy 9.9%, 135us/dispatch.)
#define FMA_HALF(v0, v1, v2, v3, kk)                                  \
    {                                                                 \
        _Pragma("unroll")                                             \
        for (int e = 0; e < 4; ++e) {                                 \
            const float b0e = ((const float*)&(v0))[e];               \
            const float b1e = ((const float*)&(v1))[e];               \
            const float b2e = ((const float*)&(v2))[e];               \
            const float b3e = ((const float*)&(v3))[e];               \
            _Pragma("unroll")                                         \
            for (int r = 0; r < RCH; ++r) {                           \
                const float a = As[(kk) + e][r];                      \
                acc[0][r] = fmaf(b0e, a, acc[0][r]);                  \
                acc[1][r] = fmaf(b1e, a, acc[1][r]);                  \
                acc[2][r] = fmaf(b2e, a, acc[2][r]);                  \
                acc[3][r] = fmaf(b3e, a, acc[3][r]);                  \
            }                                                         \
        }                                                             \
    }

__global__ __launch_bounds__(256)
void rescue_kernel(const float* __restrict__ src, const float* __restrict__ cb,
                   const float* __restrict__ norms_s,
                   const int* __restrict__ list, const int* __restrict__ nflag_p,
                   int* __restrict__ idx_i, float* __restrict__ idx_f, int q)
{
    __shared__ float As[D_][RCH];      // residual rows, [k][row] (16 KB)
    __shared__ int   rows_s[RCH];
    __shared__ float wm[4][RCH];
    __shared__ int   wi[4][RCH];
    const int nflag = nflag_p[0];
    const int tid = threadIdx.x;

    // 4 independent code streams per thread: tid + 256*j
    const float* const c0 = cb + (size_t)(tid      ) * D_;
    const float* const c1 = cb + (size_t)(tid + 256) * D_;
    const float* const c2 = cb + (size_t)(tid + 512) * D_;
    const float* const c3 = cb + (size_t)(tid + 768) * D_;

    for (int chunk = blockIdx.x; chunk * RCH < nflag; chunk += gridDim.x) {
        __syncthreads();
        if (tid < RCH) {
            const int li = chunk * RCH + tid;
            rows_s[tid] = list[li < nflag ? li : nflag - 1];   // pad = dup last
        }
        __syncthreads();
        #pragma unroll
        for (int i = 0; i < 4; ++i) {
            const int v  = tid + 256 * i;
            const int r  = v >> 7;
            const int k4 = (v & 127) * 4;
            float4 f = *(const float4*)(src + (size_t)rows_s[r] * D_ + k4);
            As[k4 + 0][r] = f.x; As[k4 + 1][r] = f.y;
            As[k4 + 2][r] = f.z; As[k4 + 3][r] = f.w;
        }
        __syncthreads();

        float acc[4][RCH];
        #pragma unroll
        for (int j = 0; j < 4; ++j)
            #pragma unroll
            for (int r = 0; r < RCH; ++r) acc[j][r] = 0.f;

        // pipelined dot over k: issue loads for the other half before FMA
        float4 pa0 = *(const float4*)(c0);
        float4 pa1 = *(const float4*)(c1);
        float4 pa2 = *(const float4*)(c2);
        float4 pa3 = *(const float4*)(c3);
        for (int k = 0; k < D_; k += 8) {
            float4 pb0 = *(const float4*)(c0 + k + 4);
            float4 pb1 = *(const float4*)(c1 + k + 4);
            float4 pb2 = *(const float4*)(c2 + k + 4);
            float4 pb3 = *(const float4*)(c3 + k + 4);
            FMA_HALF(pa0, pa1, pa2, pa3, k);
            if (k + 8 < D_) {
                pa0 = *(const float4*)(c0 + k + 8);
                pa1 = *(const float4*)(c1 + k + 8);
                pa2 = *(const float4*)(c2 + k + 8);
                pa3 = *(const float4*)(c3 + k + 8);
            }
            FMA_HALF(pb0, pb1, pb2, pb3, k + 4);
        }

        float m1[RCH]; int i1[RCH];
        #pragma unroll
        for (int r = 0; r < RCH; ++r) { m1[r] = INFINITY; i1[r] = 0; }
        #pragma unroll
        for (int j = 0; j < 4; ++j) {
            const int c = tid + 256 * j;
            const float nr = norms_s[c];
            #pragma unroll
            for (int r = 0; r < RCH; ++r) {
                const float s = fmaf(-2.f, acc[j][r], nr);
                if (s < m1[r]) { m1[r] = s; i1[r] = c; }
            }
        }
        #pragma unroll
        for (int d = 1; d < 64; d <<= 1)
            #pragma unroll
            for (int r = 0; r < RCH; ++r) {
                const float om = __shfl_xor(m1[r], d);
                const int   oi = __shfl_xor(i1[r], d);
                if (om < m1[r] || (om == m1[r] && oi < i1[r])) { m1[r] = om; i1[r] = oi; }
            }
        if ((tid & 63) == 0)
            #pragma unroll
            for (int r = 0; r < RCH; ++r) { wm[tid >> 6][r] = m1[r]; wi[tid >> 6][r] = i1[r]; }
        __syncthreads();
        if (tid < RCH) {
            float bm = wm[0][tid]; int bi = wi[0][tid];
            #pragma unroll
            for (int w = 1; w < 4; ++w)
                if (wm[w][tid] < bm || (wm[w][tid] == bm && wi[w][tid] < bi)) {
                    bm = wm[w][tid]; bi = wi[w][tid];
                }
            const int li = chunk * RCH + tid;
            if (li < nflag) {
                const int row = rows_s[tid];
                idx_i[row] = bi;
                idx_f[(size_t)row * Q_ + q] = (float)bi;
            }
        }
    }
}

// -------------------------------------------------------------------------
// residual update: newres = res - cb[idx] (exact f32); loss; final qout.
// write_hl: also emit bf16 HI of newres for next stage's GEMM A (lo not needed).
__global__ __launch_bounds__(256)
void update_kernel(const float* __restrict__ src, float* __restrict__ dst,
                   const float* __restrict__ x, const float* __restrict__ cb,
                   const int* __restrict__ idx_i, float* __restrict__ loss_out,
                   unsigned short* __restrict__ rhi,
                   int is_last, int write_hl) {
    __shared__ int ids[64];
    const int tid = threadIdx.x;
    const int rowBase = blockIdx.x * 64;
    if (tid < 64) ids[tid] = idx_i[rowBase + tid];
    __syncthreads();
    float lsum = 0.f;
    #pragma unroll 4
    for (int e4 = tid; e4 < 64 * D_ / 4; e4 += 256) {
        const int row  = e4 >> 7;
        const int d    = (e4 & 127) * 4;
        const int code = ids[row];
        const size_t off = (size_t)(rowBase + row) * D_ + d;
        float4 r = *(const float4*)(src + off);
        float4 e = *(const float4*)(cb + (size_t)code * D_ + d);
        float4 nr = make_float4(r.x - e.x, r.y - e.y, r.z - e.z, r.w - e.w);
        lsum += nr.x * nr.x + nr.y * nr.y + nr.z * nr.z + nr.w * nr.w;
        if (is_last) {
            float4 xv = *(const float4*)(x + off);
            *(float4*)(dst + off) = make_float4(xv.x - nr.x, xv.y - nr.y,
                                                xv.z - nr.z, xv.w - nr.w);
        } else {
            *(float4*)(dst + off) = nr;
        }
        if (write_hl) {
            ushort4 h;
            h.x = bf16rn(nr.x);
            h.y = bf16rn(nr.y);
            h.z = bf16rn(nr.z);
            h.w = bf16rn(nr.w);
            *(ushort4*)(rhi + off) = h;
        }
    }
    #pragma unroll
    for (int m = 1; m < 64; m <<= 1) lsum += __shfl_xor(lsum, m);
    if ((tid & 63) == 0)
        atomicAdd(loss_out, lsum * (1.0f / ((float)ROWS * (float)D_)));
}

// -------------------------------------------------------------------------
extern "C" void kernel_launch(void* const* d_in, const int* in_sizes, int n_in,
                              void* d_out, int out_size, void* d_ws, size_t ws_size,
                              hipStream_t stream) {
    const float* x  = (const float*)d_in[0];   // [B,N,D]
    const float* cb = (const float*)d_in[1];   // [Q,C,D]

    float* qout   = (float*)d_out;                                  // doubles as residual
    float* idx_f  = (float*)d_out + (size_t)ROWS * D_;              // [ROWS][Q_] as floats
    float* losses = idx_f + (size_t)ROWS * Q_;                      // [Q_]

    char* w = (char*)d_ws;
    unsigned short* cb_hi = (unsigned short*)w;                     // Q*C*D bf16 (8MB)
    unsigned short* cb_lo = cb_hi + (size_t)Q_ * C_ * D_;           // 8MB
    float* norms = (float*)(cb_lo + (size_t)Q_ * C_ * D_);          // Q*C
    float* st_m1 = norms + Q_ * C_;                                 // 4*ROWS
    float* st_m2 = st_m1 + 4 * ROWS;
    int*   st_i1 = (int*)(st_m2 + 4 * ROWS);
    int*   idx_i = st_i1 + 4 * ROWS;                                // ROWS
    int*   list  = idx_i + ROWS;                                    // ROWS
    int*   nflag = list + ROWS;                                     // 8 counters + pad
    unsigned short* res_hi = (unsigned short*)(nflag + 64);         // ROWS*D (32MB)
    unsigned short* res_lo = res_hi + (size_t)ROWS * D_;            // 32MB (stage-0 scratch)

    const size_t need = (size_t)((char*)(res_lo + (size_t)ROWS * D_) - w);
    const int preconv = (ws_size >= need) ? 1 : 0;

    hipMemsetAsync(losses, 0, Q_ * sizeof(float), stream);
    hipMemsetAsync(nflag, 0, 8 * sizeof(int), stream);   // all stages' counters
    cb_convert_kernel<<<Q_ * C_ * D_ / 1024, 256, 0, stream>>>(cb, cb_hi, cb_lo);
    code_norms_kernel<<<Q_ * C_ / 4, 256, 0, stream>>>(cb, norms);
    if (preconv)   // stage-0 A = x (lo written to scratch, unused)
        cb_convert_kernel<<<(int)((size_t)ROWS * D_ / 1024), 256, 0, stream>>>(x, res_hi, res_lo);

    for (int q = 0; q < Q_; ++q) {
        const float* src = (q == 0) ? x : qout;
        const float* cb_s = cb + (size_t)q * C_ * D_;
        if (preconv)
            rvq_gemm_pipe_kernel<<<dim3(ROWS / 128, 2), 256, 0, stream>>>(
                res_hi,
                cb_hi + (size_t)q * C_ * D_, cb_lo + (size_t)q * C_ * D_,
                norms + (size_t)q * C_, st_m1, st_m2, st_i1);
        else
            rvq_gemm_fallback_kernel<<<dim3(ROWS / 128, 2), 256, 0, stream>>>(
                src, cb_hi + (size_t)q * C_ * D_, cb_lo + (size_t)q * C_ * D_,
                norms + (size_t)q * C_, st_m1, st_m2, st_i1);
        merge_kernel<<<ROWS / 256, 256, 0, stream>>>(
            st_m1, st_m2, st_i1, idx_i, idx_f, list, nflag + q, q);
        rescue_kernel<<<256, 256, 0, stream>>>(
            src, cb_s, norms + (size_t)q * C_, list, nflag + q, idx_i, idx_f, q);
        update_kernel<<<ROWS / 64, 256, 0, stream>>>(
            src, qout, x, cb_s, idx_i, losses + q, res_hi,
            (q == Q_ - 1) ? 1 : 0, (preconv && q < Q_ - 1) ? 1 : 0);
    }
}